// Round 2
// baseline (287.496 us; speedup 1.0000x reference)
//
#include <hip/hip_runtime.h>
#include <cmath>

#ifndef M_PI
#define M_PI 3.14159265358979323846
#endif

#define NIMG 512
#define NRHO 1024
#define NTH  512
#define ZROWS 256           // theta bins kept (bin 256 zeroed by zeta -> dropped)
#define GROWS 256           // gk theta rows kept: fx in [128,384) only
#define S4   520            // LDS row stride (float2) for 4-row pair kernels
#define PTOT (1024*512)     // n_angles * n_det
#define NSPAN 3

// ---------------- host-side scalar constants ----------------
struct Consts { double G_LA, d_rho, aR, dth, constv; };

static Consts compute_consts() {
  Consts c;
  const double beta = M_PI / 3.0;
  const double sb = sin(beta / 2.0), cb = cos(beta / 2.0);
  const double aR = sb / (1.0 + sb);
  const double am = (cb - sb) / (1.0 + sb);
  double g = -1e300;
  const double start = -M_PI / 2.0, stop = M_PI / 2.0;
  const double delta = (stop - start) / 999.0;
  for (int i = 0; i < 1000; ++i) {
    double t = (i == 999) ? stop : (double)i * delta + start;
    double wre = aR * cos(t) + (1.0 - aR);
    double wim = aR * sin(t);
    double v = log(hypot(wre, wim)) + log(cos(beta / 2.0 - atan2(wim, wre)));
    if (!std::isnan(v) && v > g) g = v;
  }
  c.aR    = aR;
  c.G_LA  = g - log(am);
  c.d_rho = c.G_LA / 1024.0;
  double t1 = (-1023.0 / 2048.0) * beta * 2.0;
  double t0 = (-1024.0 / 2048.0) * beta * 2.0;
  c.dth = t1 - t0;
  c.constv = sqrt(0.5) * M_PI / 4.0 / aR / sqrt(2.0);
  return c;
}
static const Consts g_C = compute_consts();

// ---------------- device helpers ----------------
__device__ __forceinline__ float2 cmulf(float2 a, float2 b) {
  return make_float2(a.x * b.x - a.y * b.y, a.x * b.y + a.y * b.x);
}
__device__ __forceinline__ float2 cmulcf(float2 a, float2 w) {   // a * conj(w)
  return make_float2(a.x * w.x + a.y * w.y, a.y * w.x - a.x * w.y);
}
__device__ __forceinline__ int SW(int i) { return i ^ ((i >> 5) & 31); }  // XOR bank swizzle
__device__ __forceinline__ int PD(int i) { return i + (i >> 4); }         // pad-per-16 permutation
__device__ __forceinline__ int dr4_10(int v) {                    // reverse 5 base-4 digits
  int r = 0;
  #pragma unroll
  for (int k = 0; k < 5; ++k) { r = (r << 2) | (v & 3); v >>= 2; }
  return r;
}
__device__ __forceinline__ double h_val(int jj) {
  const double ctab[11] = {-216254335.0, 679543284.0, -1412947389.0, 2415881496.0,
                           -3103579086.0, 2939942400.0, -2023224114.0, 984515304.0,
                           -321455811.0, 63253516.0, -5675265.0};
  int j = -1;
  if (jj <= 10) j = jj;
  else if (jj >= 2038) j = 2048 - jj;
  if (j < 0) return 1.0;
  double c = 1.0 + ctab[j] / 958003200.0;
  if (j == 0) c = 2.0 * (c - 0.5);
  return c;
}

// ---------------- precompute: L/amp tables + fp32 twiddle tables ----------------
__global__ __launch_bounds__(256) void k_pre(double* __restrict__ Ltab,
                                             double* __restrict__ amp,
                                             float2* __restrict__ tw1024f,
                                             float2* __restrict__ tw2048f) {
  int id = blockIdx.x * 256 + threadIdx.x;
  const double beta = M_PI / 3.0;
  if (id < 2048) {
    double th = ((double)(id - 1024) / 2048.0) * beta * 2.0;
    double L = log(cos(th));
    Ltab[id] = L;
    amp[id]  = h_val(id) * exp(-L);
  }
  if (id < 1024) {
    double a1 = -2.0 * M_PI * (double)id / 1024.0;
    double a2 = -2.0 * M_PI * (double)id / 2048.0;
    double s1, c1, s2, c2;
    sincos(a1, &s1, &c1); sincos(a2, &s2, &c2);
    tw1024f[id] = make_float2((float)c1, (float)s1);
    tw2048f[id] = make_float2((float)c2, (float)s2);
  }
}

// ---------------- zeta: fp32 2048-pt FFT per rho-frequency row ----------------
// zetaT[j][p], j<256 theta bin, p = base-4-digit-reversed rho freq.
// Includes const*dth/b3 and both inverse-FFT normalizations.
__global__ __launch_bounds__(256) void k_zeta(const double* __restrict__ Ltab,
                                              const double* __restrict__ amp,
                                              const float2* __restrict__ tw2048f,
                                              float2* __restrict__ zetaT,
                                              double G_LA, double dth, double constv) {
  __shared__ float2 s[2048 + 128];
  __shared__ float2 twl[1024 + 64];
  const int i   = blockIdx.x;    // k_rho row 0..1023
  const int tid = threadIdx.x;
  for (int e = tid; e < 1024; e += 256) twl[PD(e)] = tw2048f[e];
  const double om = 2.0 * M_PI * (double)(i - 512) / G_LA;
  const double INV2PI = 1.0 / (2.0 * M_PI);
  for (int j = tid; j < 2048; j += 256) {
    int jj = (j + 1024) & 2047;
    double ph = -om * Ltab[jj] * INV2PI;
    ph -= floor(ph);
    float ang = (float)ph * 6.28318530717958647f;
    float sv, cv; __sincosf(ang, &sv, &cv);
    float a = (float)amp[jj];
    s[PD(__brev((unsigned)j) >> 21)] = make_float2(a * cv, a * sv);
  }
  for (int lh = 0; lh < 11; ++lh) {
    __syncthreads();
    for (int e = tid; e < 1024; e += 256) {
      int pos = e & ((1 << lh) - 1);
      int ia  = ((e >> lh) << (lh + 1)) | pos;
      float2 w = twl[PD(pos << (10 - lh))];
      float2 u = s[PD(ia)];
      float2 v = cmulf(s[PD(ia + (1 << lh))], w);
      s[PD(ia)]             = make_float2(u.x + v.x, u.y + v.y);
      s[PD(ia + (1 << lh))] = make_float2(u.x - v.x, u.y - v.y);
    }
  }
  __syncthreads();
  const int i2 = (i + 512) & 1023;
  const int p  = dr4_10(i2);
  const double b3r = (4.0 + 2.0 * cos(2.0 * M_PI * (double)i2 / 1024.0)) / 6.0;
  if (tid < 256) {
    int j2 = tid;
    float2 z = make_float2(0.f, 0.f);
    if (i != 0) {
      float2 F = s[PD(j2)];
      double b3t = (4.0 + 2.0 * cos(2.0 * M_PI * (double)j2 / 512.0)) / 6.0;
      double sc = dth * constv / (b3r * b3t) * (1.0 / (1024.0 * 512.0));
      z = make_float2((float)((double)F.x * sc), (float)((double)F.y * sc));
    }
    zetaT[(size_t)j2 * 1024 + p] = z;
  }
}

// ---------------- gather index map, ALL spans, natural theta order ----------------
__global__ __launch_bounds__(256) void k_idx_lp2c(int* __restrict__ idx1,
                                                  double d_rho, double aR) {
  int q = blockIdx.x * 256 + threadIdx.x;
  int span = q >> 19;                                // q / (NRHO*NTH)
  int ql = q & (NRHO * NTH - 1);
  int i = ql >> 9, j = ql & 511;
  const double beta = M_PI / 3.0;
  double d_th = 2.0 * beta / 512.0;
  double th = (double)(j - 256) * d_th;
  double er = exp((double)(i - 1024) * d_rho);
  double t1 = er * cos(th), t2 = er * sin(th);
  double a = (double)span * beta + beta / 2.0;
  double ca = cos(a), sa = sin(a);
  double l1 = ((t1 - (1.0 - aR)) * ca - t2 * sa) / aR;
  double l2 = -(((t1 - (1.0 - aR)) * sa + t2 * ca) / aR);
  l1 = (l1 + 1.0) / 2.0 * 511.0;
  l2 = (l2 + 1.0) / 2.0 * 511.0;
  double fy = floor(l1); fy = fy < 0.0 ? 0.0 : (fy > 510.0 ? 510.0 : fy);
  double fx = floor(l2); fx = fx < 0.0 ? 0.0 : (fx > 510.0 ? 510.0 : fx);
  idx1[q] = (int)fy * 512 + (int)fx;
}

// ---------------- gather + paired rfft(512): 8 rho-rows = 4 complex FFTs ----------------
// blockIdx.z = span. Thread tid: rho row r=tid>>5, 16 consecutive theta.
__global__ __launch_bounds__(256) void k_gather_rfft(const float* __restrict__ x,
                                                     const int* __restrict__ idx1,
                                                     const float2* __restrict__ tw1024f,
                                                     float2* __restrict__ T,
                                                     int b0, double d_rho) {
  __shared__ float2 s[4][S4];     // 16.6 KB
  __shared__ float2 twl[256];
  const int bx   = blockIdx.x;
  const int g    = ((bx & 7) << 4) | (bx >> 3);      // XCD ring swizzle (128 blocks)
  const int i0   = g * 8;
  const int lb   = blockIdx.y;
  const int span = blockIdx.z;
  const int tid  = threadIdx.x;
  twl[tid] = tw1024f[2 * tid];                       // exp(-2pi i m/512), m<256
  const int r  = tid >> 5;                           // rho row 0..7
  const int t5 = tid & 31;
  const float er = (float)exp((double)(i0 + r - 1024) * d_rho);
  const float* xb = x + (size_t)(b0 + lb) * (NIMG * NIMG);
  const int4* ip = (const int4*)(idx1 + span * (NRHO * NTH) + (i0 + r) * 512 + t5 * 16);
  int4 i4[4];
  #pragma unroll
  for (int u = 0; u < 4; ++u) i4[u] = ip[u];
  float v[16];
  #pragma unroll
  for (int u = 0; u < 4; ++u) {                      // 16 gathers issued back-to-back
    v[4 * u + 0] = xb[i4[u].x];
    v[4 * u + 1] = xb[i4[u].y];
    v[4 * u + 2] = xb[i4[u].z];
    v[4 * u + 3] = xb[i4[u].w];
  }
  float* sm = (float*)s[r >> 1];
  const int p = r & 1;
  #pragma unroll
  for (int u = 0; u < 16; ++u) {
    int j = t5 * 16 + u;
    int slot = __brev((unsigned)j) >> 23;            // bit-reversal for free
    sm[2 * SW(slot) + p] = v[u] * er;
  }
  // 4 complex FFT-512, radix-2 DIT (input bit-reversed, output natural)
  for (int lh = 0; lh < 9; ++lh) {
    __syncthreads();
    for (int it = 0; it < 4; ++it) {
      int e = tid + (it << 8);
      int m = e >> 8, b = e & 255;
      int pos = b & ((1 << lh) - 1);
      int ia  = ((b >> lh) << (lh + 1)) | pos;
      float2 w = twl[pos << (8 - lh)];
      float2* smm = s[m];
      float2 u = smm[SW(ia)];
      float2 vv = cmulf(smm[SW(ia + (1 << lh))], w);
      smm[SW(ia)]             = make_float2(u.x + vv.x, u.y + vv.y);
      smm[SW(ia + (1 << lh))] = make_float2(u.x - vv.x, u.y - vv.y);
    }
  }
  __syncthreads();
  // unpack pair spectra + transposed coalesced write (64B per theta bin)
  float2* Tb = T + (size_t)(span * gridDim.y + lb) * (ZROWS * NRHO);
  for (int it = 0; it < 8; ++it) {
    int e = tid + (it << 8);                         // 0..2047
    int k = e >> 3, rr = e & 7;
    int m = rr >> 1, pp = rr & 1;
    float2 Z  = s[m][SW(k)];
    float2 Zc = s[m][SW((512 - k) & 511)];
    float2 F;
    if (!pp) F = make_float2(0.5f * (Z.x + Zc.x), 0.5f * (Z.y - Zc.y));
    else     F = make_float2(0.5f * (Z.y + Zc.y), 0.5f * (Zc.x - Z.x));
    Tb[(size_t)k * NRHO + i0 + rr] = F;
  }
}

// ---------------- rho: fft1024 * zeta * ifft1024, radix-4, TWO theta-bins/block ----------------
// Each thread does one radix-4 butterfly per bin per stage: 2x work per barrier vs
// one-bin/block, half the twiddle-load traffic, half the block count.
// LDS indices pass through PD() pad-permutation: 4-way worst-case banks vs 16-way raw.
__global__ __launch_bounds__(256) void k_fft_rho(float2* __restrict__ T,
                                                 const float2* __restrict__ zetaT,
                                                 const float2* __restrict__ tw1024f) {
  __shared__ float2 s[2][1024 + 64];
  __shared__ float2 twl[1024 + 64];
  const int j0   = blockIdx.x * 2;                   // two consecutive theta bins
  const int lb   = blockIdx.y;
  const int span = blockIdx.z;
  const int tid  = threadIdx.x;
  for (int e = tid; e < 1024; e += 256) twl[PD(e)] = tw1024f[e];
  float2* row0 = T + ((size_t)(span * gridDim.y + lb) * ZROWS + j0) * NRHO;
  #pragma unroll
  for (int m = 0; m < 2; ++m) {
    const float4* rp = (const float4*)(row0 + (size_t)m * NRHO);
    for (int e = tid; e < 512; e += 256) {
      float4 v = rp[e];
      s[m][PD(2 * e)]     = make_float2(v.x, v.y);
      s[m][PD(2 * e + 1)] = make_float2(v.z, v.w);
    }
  }
  __syncthreads();
  #pragma unroll
  for (int lq = 8; lq >= 0; lq -= 2) {
    const int q = 1 << lq, tfac = 256 >> lq;
    int jj = tid & (q - 1);
    int base = ((tid >> lq) << (lq + 2)) | jj;
    int t1i = jj * tfac;
    float2 w1 = twl[PD(t1i)], w2 = twl[PD(2 * t1i)], w3 = twl[PD(3 * t1i)];
    #pragma unroll
    for (int m = 0; m < 2; ++m) {
      float2* sm = s[m];
      float2 a = sm[PD(base)], b = sm[PD(base + q)];
      float2 c = sm[PD(base + 2 * q)], d = sm[PD(base + 3 * q)];
      float2 A = make_float2(a.x + c.x, a.y + c.y);
      float2 C = make_float2(a.x - c.x, a.y - c.y);
      float2 B = make_float2(b.x + d.x, b.y + d.y);
      float2 D = make_float2(b.x - d.x, b.y - d.y);
      float2 u0 = make_float2(A.x + B.x, A.y + B.y);
      float2 u2 = make_float2(A.x - B.x, A.y - B.y);
      float2 u1 = make_float2(C.x + D.y, C.y - D.x);
      float2 u3 = make_float2(C.x - D.y, C.y + D.x);
      sm[PD(base)]         = u0;
      sm[PD(base + q)]     = cmulf(u1, w1);
      sm[PD(base + 2 * q)] = cmulf(u2, w2);
      sm[PD(base + 3 * q)] = cmulf(u3, w3);
    }
    __syncthreads();
  }
  #pragma unroll
  for (int m = 0; m < 2; ++m) {
    const float2* zrow = zetaT + (size_t)(j0 + m) * NRHO;
    for (int e = tid; e < 1024; e += 256)
      s[m][PD(e)] = cmulf(s[m][PD(e)], zrow[e]);
  }
  __syncthreads();
  #pragma unroll
  for (int lq = 0; lq <= 8; lq += 2) {
    const int q = 1 << lq, tfac = 256 >> lq;
    int jj = tid & (q - 1);
    int base = ((tid >> lq) << (lq + 2)) | jj;
    int t1i = jj * tfac;
    float2 w1 = twl[PD(t1i)], w2 = twl[PD(2 * t1i)], w3 = twl[PD(3 * t1i)];
    #pragma unroll
    for (int m = 0; m < 2; ++m) {
      float2* sm = s[m];
      float2 u0 = sm[PD(base)];
      float2 u1 = cmulcf(sm[PD(base + q)],     w1);
      float2 u2 = cmulcf(sm[PD(base + 2 * q)], w2);
      float2 u3 = cmulcf(sm[PD(base + 3 * q)], w3);
      float2 t0 = make_float2(u0.x + u2.x, u0.y + u2.y);
      float2 t1 = make_float2(u0.x - u2.x, u0.y - u2.y);
      float2 t2 = make_float2(u1.x + u3.x, u1.y + u3.y);
      float2 t3 = make_float2(u1.x - u3.x, u1.y - u3.y);
      sm[PD(base)]         = make_float2(t0.x + t2.x, t0.y + t2.y);
      sm[PD(base + 2 * q)] = make_float2(t0.x - t2.x, t0.y - t2.y);
      sm[PD(base + q)]     = make_float2(t1.x - t3.y, t1.y + t3.x);
      sm[PD(base + 3 * q)] = make_float2(t1.x + t3.y, t1.y - t3.x);
    }
    __syncthreads();
  }
  #pragma unroll
  for (int m = 0; m < 2; ++m) {
    float4* rp = (float4*)(row0 + (size_t)m * NRHO);
    for (int e = tid; e < 512; e += 256) {
      float2 a = s[m][PD(2 * e)], b = s[m][PD(2 * e + 1)];
      rp[e] = make_float4(a.x, a.y, b.x, b.y);
    }
  }
}

// ---------------- paired Hermitian irfft(512): 8 rho-rows = 4 complex IFFTs ----------------
// Only theta rows 128..383 are ever sampled by the scatter -> write just those,
// COMPACTED (row j-128) and in natural theta order.
__global__ __launch_bounds__(256) void k_irfft_th(const float2* __restrict__ T,
                                                  const float2* __restrict__ tw1024f,
                                                  float* __restrict__ gkT) {
  __shared__ float2 s[4][S4];
  __shared__ float2 twl[256];
  const int i0   = blockIdx.x * 8;
  const int lb   = blockIdx.y;
  const int span = blockIdx.z;
  const int tid  = threadIdx.x;
  twl[tid] = tw1024f[2 * tid];
  const float2* Tb = T + (size_t)(span * gridDim.y + lb) * (ZROWS * NRHO);
  __syncthreads();
  // stage A: raw F -> LDS (pair m holds F0 at SW(k), F1 at SW(256+k))
  for (int it = 0; it < 8; ++it) {
    int e = tid + (it << 8);
    int k = e >> 3, rr = e & 7;
    int m = rr >> 1, p = rr & 1;
    s[m][SW(k + 256 * p)] = Tb[(size_t)k * NRHO + i0 + rr];
  }
  __syncthreads();
  // stage B: build Z = F0 + i*F1 over k=0..511 (registers to avoid in-place hazard)
  float2 Zr[8];
  for (int it = 0; it < 8; ++it) {
    int e = tid + (it << 8);
    int m = e >> 9, k = e & 511;
    float2 z;
    if (k == 256) z = make_float2(0.f, 0.f);
    else {
      int k2 = (k < 256) ? k : 512 - k;
      float2 F0 = s[m][SW(k2)];
      float2 F1 = s[m][SW(256 + k2)];
      if (k2 == 0) { F0.y = 0.f; F1.y = 0.f; }       // numpy irfft ignores DC imag
      if (k < 256) z = make_float2(F0.x - F1.y, F0.y + F1.x);
      else         z = make_float2(F0.x + F1.y, F1.x - F0.y);
    }
    Zr[it] = z;
  }
  __syncthreads();
  for (int it = 0; it < 8; ++it) {
    int e = tid + (it << 8);
    int m = e >> 9, k = e & 511;
    s[m][SW(k)] = Zr[it];
  }
  // inverse DIF (sign +): natural in -> bit-reversed out
  for (int lh = 8; lh >= 0; --lh) {
    __syncthreads();
    for (int it = 0; it < 4; ++it) {
      int e = tid + (it << 8);
      int m = e >> 8, b = e & 255;
      int pos = b & ((1 << lh) - 1);
      int ia  = ((b >> lh) << (lh + 1)) | pos;
      float2 w = twl[pos << (8 - lh)];
      float2* sm = s[m];
      float2 u = sm[SW(ia)];
      float2 v = sm[SW(ia + (1 << lh))];
      sm[SW(ia)] = make_float2(u.x + v.x, u.y + v.y);
      float2 d = make_float2(u.x - v.x, u.y - v.y);
      sm[SW(ia + (1 << lh))] = cmulcf(d, w);
    }
  }
  __syncthreads();
  // write ONLY theta rows 128..383, compacted+natural order (2048 values)
  float* gb = gkT + (size_t)(span * gridDim.y + lb) * (GROWS * NRHO);
  for (int it = 0; it < 8; ++it) {
    int e = tid + (it << 8);                         // 0..2047
    int ro = e >> 3, rr = e & 7;                     // ro = j-128
    int j = ro + 128;
    int jslot = __brev((unsigned)j) >> 23;           // DIF output slot of theta j
    float2 z = s[rr >> 1][SW(jslot)];
    gb[(size_t)ro * NRHO + i0 + rr] = (rr & 1) ? z.y : z.x;
  }
}

// ---------------- resample to (angle, det), ALL spans in one dispatch ----------------
// Span of angle t: k = (3t)>>10 (exact partition; boundaries never integral).
// gkT rows are compacted: row = fx - 128 (fx proven in [128,384)).
__global__ __launch_bounds__(256) void k_scatter(const float* __restrict__ gkT,
                                                 float* __restrict__ out,
                                                 int b0, int chunk,
                                                 double d_rho, double aR) {
  int p = blockIdx.x * 256 + threadIdx.x;
  if (p >= PTOT) return;
  const int t = p >> 9;
  const int d = p & 511;
  const int span = (3 * t) >> 10;
  const double beta = M_PI / 3.0;
  double th0 = (double)t * M_PI / 1024.0 - beta / 2.0;
  double th00 = th0 - (double)span * beta;
  double d_th = 2.0 * beta / 512.0;
  double th_lp0 = -256.0 * d_th, th_lpL = 255.0 * d_th;
  double p1 = (th00 - th_lp0) / (th_lpL - th_lp0) * 511.0;
  double s0v = (d == 511) ? 1.0 : (double)d * (2.0 / 511.0) - 1.0;
  double p2 = log(s0v * aR + (1.0 - aR) * cos(th00));
  double rho0 = -1024.0 * d_rho, rhoL = -1.0 * d_rho;
  p2 = (p2 - rho0) / (rhoL - rho0) * 1023.0;
  double fy = floor(p2); fy = fy < 0.0 ? 0.0 : (fy > 1022.0 ? 1022.0 : fy);
  double fx = floor(p1); fx = fx < 0.0 ? 0.0 : (fx > 510.0 ? 510.0 : fx);
  int idx = ((int)fx - 128) * 1024 + (int)fy;        // compacted natural-order row
  const float* gsp = gkT + (size_t)span * chunk * (GROWS * NRHO);
  for (int lb = 0; lb < chunk; ++lb)
    out[(size_t)(b0 + lb) * PTOT + p] = gsp[(size_t)lb * (GROWS * NRHO) + idx];
}

// ---------------- launch ----------------
extern "C" void kernel_launch(void* const* d_in, const int* in_sizes, int n_in,
                              void* d_out, int out_size, void* d_ws, size_t ws_size,
                              hipStream_t stream) {
  (void)n_in; (void)out_size;
  const float* x = (const float*)d_in[0];
  float* out = (float*)d_out;
  const int batch = in_sizes[0] / (NIMG * NIMG);

  const size_t zeta_b = (size_t)ZROWS * NRHO * sizeof(float2);          // 2 MB
  const size_t idx_b  = (size_t)NSPAN * NRHO * NTH * sizeof(int);       // 6 MB
  const size_t tab_b  = 2048 * sizeof(double) * 2 + 1024 * sizeof(float2) * 2;
  const size_t per_b  = (size_t)NSPAN * ((size_t)ZROWS * NRHO * sizeof(float2)
                      + (size_t)GROWS * NRHO * sizeof(float));          // 9 MB / image
  int chunk = batch;
  while (chunk > 1 && zeta_b + idx_b + tab_b + (size_t)chunk * per_b > ws_size) chunk >>= 1;

  char* ws = (char*)d_ws;
  float2* zetaT   = (float2*)ws;  ws += zeta_b;
  int*    idx1    = (int*)ws;     ws += idx_b;
  double* Ltab    = (double*)ws;  ws += 2048 * sizeof(double);
  double* amp     = (double*)ws;  ws += 2048 * sizeof(double);
  float2* tw1024f = (float2*)ws;  ws += 1024 * sizeof(float2);
  float2* tw2048f = (float2*)ws;  ws += 1024 * sizeof(float2);
  float2* T       = (float2*)ws;  ws += (size_t)NSPAN * chunk * ZROWS * NRHO * sizeof(float2);
  float*  gkT     = (float*)ws;

  k_pre     <<<dim3(8),    dim3(256), 0, stream>>>(Ltab, amp, tw1024f, tw2048f);
  k_zeta    <<<dim3(1024), dim3(256), 0, stream>>>(Ltab, amp, tw2048f, zetaT,
                                                   g_C.G_LA, g_C.dth, g_C.constv);
  k_idx_lp2c<<<dim3((NSPAN * NRHO * NTH) / 256), dim3(256), 0, stream>>>(idx1, g_C.d_rho, g_C.aR);

  for (int b0 = 0; b0 < batch; b0 += chunk) {
    int c = (b0 + chunk <= batch) ? chunk : (batch - b0);
    k_gather_rfft<<<dim3(NRHO / 8, c, NSPAN), dim3(256), 0, stream>>>(x, idx1, tw1024f, T, b0, g_C.d_rho);
    k_fft_rho    <<<dim3(ZROWS / 2, c, NSPAN), dim3(256), 0, stream>>>(T, zetaT, tw1024f);
    k_irfft_th   <<<dim3(NRHO / 8, c, NSPAN), dim3(256), 0, stream>>>(T, tw1024f, gkT);
    k_scatter    <<<dim3(PTOT / 256), dim3(256), 0, stream>>>(gkT, out, b0, c,
                                                              g_C.d_rho, g_C.aR);
  }
}

// Round 3
// 283.901 us; speedup vs baseline: 1.0127x; 1.0127x over previous
//
#include <hip/hip_runtime.h>
#include <cmath>

#ifndef M_PI
#define M_PI 3.14159265358979323846
#endif

#define NIMG 512
#define NRHO 1024
#define NTH  512
#define ZROWS 256           // theta bins kept (bin 256 zeroed by zeta -> dropped)
#define GROWS 256           // gk theta rows kept: fx in [128,384) only
#define S4   520            // LDS row stride (float2) for 4-row pair kernels
#define PTOT (1024*512)     // n_angles * n_det
#define NSPAN 3

// ---------------- host-side scalar constants ----------------
struct Consts { double G_LA, d_rho, aR, dth, constv; };

static Consts compute_consts() {
  Consts c;
  const double beta = M_PI / 3.0;
  const double sb = sin(beta / 2.0), cb = cos(beta / 2.0);
  const double aR = sb / (1.0 + sb);
  const double am = (cb - sb) / (1.0 + sb);
  double g = -1e300;
  const double start = -M_PI / 2.0, stop = M_PI / 2.0;
  const double delta = (stop - start) / 999.0;
  for (int i = 0; i < 1000; ++i) {
    double t = (i == 999) ? stop : (double)i * delta + start;
    double wre = aR * cos(t) + (1.0 - aR);
    double wim = aR * sin(t);
    double v = log(hypot(wre, wim)) + log(cos(beta / 2.0 - atan2(wim, wre)));
    if (!std::isnan(v) && v > g) g = v;
  }
  c.aR    = aR;
  c.G_LA  = g - log(am);
  c.d_rho = c.G_LA / 1024.0;
  double t1 = (-1023.0 / 2048.0) * beta * 2.0;
  double t0 = (-1024.0 / 2048.0) * beta * 2.0;
  c.dth = t1 - t0;
  c.constv = sqrt(0.5) * M_PI / 4.0 / aR / sqrt(2.0);
  return c;
}
static const Consts g_C = compute_consts();

// ---------------- device helpers ----------------
__device__ __forceinline__ float2 cmulf(float2 a, float2 b) {
  return make_float2(a.x * b.x - a.y * b.y, a.x * b.y + a.y * b.x);
}
__device__ __forceinline__ float2 cmulcf(float2 a, float2 w) {   // a * conj(w)
  return make_float2(a.x * w.x + a.y * w.y, a.y * w.x - a.x * w.y);
}
__device__ __forceinline__ int SW(int i) { return i ^ ((i >> 5) & 31); }  // XOR bank swizzle
__device__ __forceinline__ int PD(int i) { return i + (i >> 4); }         // pad-per-16 permutation
__device__ __forceinline__ int dr4_10(int v) {                    // reverse 5 base-4 digits
  int r = 0;
  #pragma unroll
  for (int k = 0; k < 5; ++k) { r = (r << 2) | (v & 3); v >>= 2; }
  return r;
}
__device__ __forceinline__ double h_val(int jj) {
  const double ctab[11] = {-216254335.0, 679543284.0, -1412947389.0, 2415881496.0,
                           -3103579086.0, 2939942400.0, -2023224114.0, 984515304.0,
                           -321455811.0, 63253516.0, -5675265.0};
  int j = -1;
  if (jj <= 10) j = jj;
  else if (jj >= 2038) j = 2048 - jj;
  if (j < 0) return 1.0;
  double c = 1.0 + ctab[j] / 958003200.0;
  if (j == 0) c = 2.0 * (c - 0.5);
  return c;
}

// ---------------- precompute: L/amp tables + fp32 twiddle tables ----------------
__global__ __launch_bounds__(256) void k_pre(double* __restrict__ Ltab,
                                             double* __restrict__ amp,
                                             float2* __restrict__ tw1024f,
                                             float2* __restrict__ tw2048f) {
  int id = blockIdx.x * 256 + threadIdx.x;
  const double beta = M_PI / 3.0;
  if (id < 2048) {
    double th = ((double)(id - 1024) / 2048.0) * beta * 2.0;
    double L = log(cos(th));
    Ltab[id] = L;
    amp[id]  = h_val(id) * exp(-L);
  }
  if (id < 1024) {
    double a1 = -2.0 * M_PI * (double)id / 1024.0;
    double a2 = -2.0 * M_PI * (double)id / 2048.0;
    double s1, c1, s2, c2;
    sincos(a1, &s1, &c1); sincos(a2, &s2, &c2);
    tw1024f[id] = make_float2((float)c1, (float)s1);
    tw2048f[id] = make_float2((float)c2, (float)s2);
  }
}

// ---------------- zeta: fp32 2048-pt FFT per rho-frequency row ----------------
// zetaT[j][p], j<256 theta bin, p = base-4-digit-reversed rho freq.
// Includes const*dth/b3 and both inverse-FFT normalizations.
__global__ __launch_bounds__(256) void k_zeta(const double* __restrict__ Ltab,
                                              const double* __restrict__ amp,
                                              const float2* __restrict__ tw2048f,
                                              float2* __restrict__ zetaT,
                                              double G_LA, double dth, double constv) {
  __shared__ float2 s[2048 + 128];
  __shared__ float2 twl[1024 + 64];
  const int i   = blockIdx.x;    // k_rho row 0..1023
  const int tid = threadIdx.x;
  for (int e = tid; e < 1024; e += 256) twl[PD(e)] = tw2048f[e];
  const double om = 2.0 * M_PI * (double)(i - 512) / G_LA;
  const double INV2PI = 1.0 / (2.0 * M_PI);
  for (int j = tid; j < 2048; j += 256) {
    int jj = (j + 1024) & 2047;
    double ph = -om * Ltab[jj] * INV2PI;
    ph -= floor(ph);
    float ang = (float)ph * 6.28318530717958647f;
    float sv, cv; __sincosf(ang, &sv, &cv);
    float a = (float)amp[jj];
    s[PD(__brev((unsigned)j) >> 21)] = make_float2(a * cv, a * sv);
  }
  for (int lh = 0; lh < 11; ++lh) {
    __syncthreads();
    for (int e = tid; e < 1024; e += 256) {
      int pos = e & ((1 << lh) - 1);
      int ia  = ((e >> lh) << (lh + 1)) | pos;
      float2 w = twl[PD(pos << (10 - lh))];
      float2 u = s[PD(ia)];
      float2 v = cmulf(s[PD(ia + (1 << lh))], w);
      s[PD(ia)]             = make_float2(u.x + v.x, u.y + v.y);
      s[PD(ia + (1 << lh))] = make_float2(u.x - v.x, u.y - v.y);
    }
  }
  __syncthreads();
  const int i2 = (i + 512) & 1023;
  const int p  = dr4_10(i2);
  const double b3r = (4.0 + 2.0 * cos(2.0 * M_PI * (double)i2 / 1024.0)) / 6.0;
  if (tid < 256) {
    int j2 = tid;
    float2 z = make_float2(0.f, 0.f);
    if (i != 0) {
      float2 F = s[PD(j2)];
      double b3t = (4.0 + 2.0 * cos(2.0 * M_PI * (double)j2 / 512.0)) / 6.0;
      double sc = dth * constv / (b3r * b3t) * (1.0 / (1024.0 * 512.0));
      z = make_float2((float)((double)F.x * sc), (float)((double)F.y * sc));
    }
    zetaT[(size_t)j2 * 1024 + p] = z;
  }
}

// ---------------- gather index map, ALL spans, natural theta order ----------------
__global__ __launch_bounds__(256) void k_idx_lp2c(int* __restrict__ idx1,
                                                  double d_rho, double aR) {
  int q = blockIdx.x * 256 + threadIdx.x;
  int span = q >> 19;                                // q / (NRHO*NTH)
  int ql = q & (NRHO * NTH - 1);
  int i = ql >> 9, j = ql & 511;
  const double beta = M_PI / 3.0;
  double d_th = 2.0 * beta / 512.0;
  double th = (double)(j - 256) * d_th;
  double er = exp((double)(i - 1024) * d_rho);
  double t1 = er * cos(th), t2 = er * sin(th);
  double a = (double)span * beta + beta / 2.0;
  double ca = cos(a), sa = sin(a);
  double l1 = ((t1 - (1.0 - aR)) * ca - t2 * sa) / aR;
  double l2 = -(((t1 - (1.0 - aR)) * sa + t2 * ca) / aR);
  l1 = (l1 + 1.0) / 2.0 * 511.0;
  l2 = (l2 + 1.0) / 2.0 * 511.0;
  double fy = floor(l1); fy = fy < 0.0 ? 0.0 : (fy > 510.0 ? 510.0 : fy);
  double fx = floor(l2); fx = fx < 0.0 ? 0.0 : (fx > 510.0 ? 510.0 : fx);
  idx1[q] = (int)fy * 512 + (int)fx;
}

// ---------------- gather + paired rfft(512): 8 rho-rows = 4 complex FFTs ----------------
// Forward DIT, input bit-reversed. Stages 0..7 fused as radix-4 (two radix-2 levels
// in registers; odd-pair twiddle of second level is -i*w2, a free rotation), then
// one radix-2 stage lh=8. 5 barriers / 40 LDS accesses per thread vs 9 / 72.
__global__ __launch_bounds__(256) void k_gather_rfft(const float* __restrict__ x,
                                                     const int* __restrict__ idx1,
                                                     const float2* __restrict__ tw1024f,
                                                     float2* __restrict__ T,
                                                     int b0, double d_rho) {
  __shared__ float2 s[4][S4];     // 16.6 KB
  __shared__ float2 twl[256];
  const int bx   = blockIdx.x;
  const int g    = ((bx & 7) << 4) | (bx >> 3);      // XCD ring swizzle (128 blocks)
  const int i0   = g * 8;
  const int lb   = blockIdx.y;
  const int span = blockIdx.z;
  const int tid  = threadIdx.x;
  twl[tid] = tw1024f[2 * tid];                       // exp(-2pi i m/512), m<256
  const int r  = tid >> 5;                           // rho row 0..7
  const int t5 = tid & 31;
  const float er = (float)exp((double)(i0 + r - 1024) * d_rho);
  const float* xb = x + (size_t)(b0 + lb) * (NIMG * NIMG);
  const int4* ip = (const int4*)(idx1 + span * (NRHO * NTH) + (i0 + r) * 512 + t5 * 16);
  int4 i4[4];
  #pragma unroll
  for (int u = 0; u < 4; ++u) i4[u] = ip[u];
  float v[16];
  #pragma unroll
  for (int u = 0; u < 4; ++u) {                      // 16 gathers issued back-to-back
    v[4 * u + 0] = xb[i4[u].x];
    v[4 * u + 1] = xb[i4[u].y];
    v[4 * u + 2] = xb[i4[u].z];
    v[4 * u + 3] = xb[i4[u].w];
  }
  float* sm = (float*)s[r >> 1];
  const int p = r & 1;
  #pragma unroll
  for (int u = 0; u < 16; ++u) {
    int j = t5 * 16 + u;
    int slot = __brev((unsigned)j) >> 23;            // bit-reversal for free
    sm[2 * SW(slot) + p] = v[u] * er;
  }
  // fused radix-4 stages (0,1),(2,3),(4,5),(6,7)
  #pragma unroll
  for (int lh = 0; lh < 8; lh += 2) {
    __syncthreads();
    const int q = 1 << lh;
    #pragma unroll
    for (int it = 0; it < 2; ++it) {
      int e = tid + (it << 8);                       // 0..511
      int m = e >> 7, gq = e & 127;
      int pos = gq & (q - 1);
      int base = ((gq >> lh) << (lh + 2)) | pos;
      float2 w1 = twl[pos << (8 - lh)];
      float2 w2 = twl[pos << (7 - lh)];
      float2* smm = s[m];
      float2 a = smm[SW(base)];
      float2 b = smm[SW(base + q)];
      float2 c = smm[SW(base + 2 * q)];
      float2 d = smm[SW(base + 3 * q)];
      float2 wb = cmulf(b, w1), wd = cmulf(d, w1);
      float2 t0 = make_float2(a.x + wb.x, a.y + wb.y);
      float2 t1 = make_float2(a.x - wb.x, a.y - wb.y);
      float2 t2 = make_float2(c.x + wd.x, c.y + wd.y);
      float2 t3 = make_float2(c.x - wd.x, c.y - wd.y);
      float2 z2 = cmulf(t2, w2);
      float2 p3 = cmulf(t3, w2);
      float2 z3 = make_float2(p3.y, -p3.x);          // (-i)*(w2*t3)
      smm[SW(base)]         = make_float2(t0.x + z2.x, t0.y + z2.y);
      smm[SW(base + 2 * q)] = make_float2(t0.x - z2.x, t0.y - z2.y);
      smm[SW(base + q)]     = make_float2(t1.x + z3.x, t1.y + z3.y);
      smm[SW(base + 3 * q)] = make_float2(t1.x - z3.x, t1.y - z3.y);
    }
  }
  // final radix-2 stage lh=8
  __syncthreads();
  #pragma unroll
  for (int it = 0; it < 4; ++it) {
    int e = tid + (it << 8);
    int m = e >> 8, b = e & 255;                     // pos=b, ia=b
    float2 w = twl[b];
    float2* smm = s[m];
    float2 u = smm[SW(b)];
    float2 vv = cmulf(smm[SW(b + 256)], w);
    smm[SW(b)]       = make_float2(u.x + vv.x, u.y + vv.y);
    smm[SW(b + 256)] = make_float2(u.x - vv.x, u.y - vv.y);
  }
  __syncthreads();
  // unpack pair spectra + transposed coalesced write (64B per theta bin)
  float2* Tb = T + (size_t)(span * gridDim.y + lb) * (ZROWS * NRHO);
  for (int it = 0; it < 8; ++it) {
    int e = tid + (it << 8);                         // 0..2047
    int k = e >> 3, rr = e & 7;
    int m = rr >> 1, pp = rr & 1;
    float2 Z  = s[m][SW(k)];
    float2 Zc = s[m][SW((512 - k) & 511)];
    float2 F;
    if (!pp) F = make_float2(0.5f * (Z.x + Zc.x), 0.5f * (Z.y - Zc.y));
    else     F = make_float2(0.5f * (Z.y + Zc.y), 0.5f * (Zc.x - Z.x));
    Tb[(size_t)k * NRHO + i0 + rr] = F;
  }
}

// ---------------- rho: fft1024 * zeta * ifft1024, radix-4, TWO theta-bins/block ----------------
// Each thread does one radix-4 butterfly per bin per stage: 2x work per barrier vs
// one-bin/block, half the twiddle-load traffic, half the block count.
// LDS indices pass through PD() pad-permutation: 4-way worst-case banks vs 16-way raw.
__global__ __launch_bounds__(256) void k_fft_rho(float2* __restrict__ T,
                                                 const float2* __restrict__ zetaT,
                                                 const float2* __restrict__ tw1024f) {
  __shared__ float2 s[2][1024 + 64];
  __shared__ float2 twl[1024 + 64];
  const int j0   = blockIdx.x * 2;                   // two consecutive theta bins
  const int lb   = blockIdx.y;
  const int span = blockIdx.z;
  const int tid  = threadIdx.x;
  for (int e = tid; e < 1024; e += 256) twl[PD(e)] = tw1024f[e];
  float2* row0 = T + ((size_t)(span * gridDim.y + lb) * ZROWS + j0) * NRHO;
  #pragma unroll
  for (int m = 0; m < 2; ++m) {
    const float4* rp = (const float4*)(row0 + (size_t)m * NRHO);
    for (int e = tid; e < 512; e += 256) {
      float4 v = rp[e];
      s[m][PD(2 * e)]     = make_float2(v.x, v.y);
      s[m][PD(2 * e + 1)] = make_float2(v.z, v.w);
    }
  }
  __syncthreads();
  #pragma unroll
  for (int lq = 8; lq >= 0; lq -= 2) {
    const int q = 1 << lq, tfac = 256 >> lq;
    int jj = tid & (q - 1);
    int base = ((tid >> lq) << (lq + 2)) | jj;
    int t1i = jj * tfac;
    float2 w1 = twl[PD(t1i)], w2 = twl[PD(2 * t1i)], w3 = twl[PD(3 * t1i)];
    #pragma unroll
    for (int m = 0; m < 2; ++m) {
      float2* sm = s[m];
      float2 a = sm[PD(base)], b = sm[PD(base + q)];
      float2 c = sm[PD(base + 2 * q)], d = sm[PD(base + 3 * q)];
      float2 A = make_float2(a.x + c.x, a.y + c.y);
      float2 C = make_float2(a.x - c.x, a.y - c.y);
      float2 B = make_float2(b.x + d.x, b.y + d.y);
      float2 D = make_float2(b.x - d.x, b.y - d.y);
      float2 u0 = make_float2(A.x + B.x, A.y + B.y);
      float2 u2 = make_float2(A.x - B.x, A.y - B.y);
      float2 u1 = make_float2(C.x + D.y, C.y - D.x);
      float2 u3 = make_float2(C.x - D.y, C.y + D.x);
      sm[PD(base)]         = u0;
      sm[PD(base + q)]     = cmulf(u1, w1);
      sm[PD(base + 2 * q)] = cmulf(u2, w2);
      sm[PD(base + 3 * q)] = cmulf(u3, w3);
    }
    __syncthreads();
  }
  #pragma unroll
  for (int m = 0; m < 2; ++m) {
    const float2* zrow = zetaT + (size_t)(j0 + m) * NRHO;
    for (int e = tid; e < 1024; e += 256)
      s[m][PD(e)] = cmulf(s[m][PD(e)], zrow[e]);
  }
  __syncthreads();
  #pragma unroll
  for (int lq = 0; lq <= 8; lq += 2) {
    const int q = 1 << lq, tfac = 256 >> lq;
    int jj = tid & (q - 1);
    int base = ((tid >> lq) << (lq + 2)) | jj;
    int t1i = jj * tfac;
    float2 w1 = twl[PD(t1i)], w2 = twl[PD(2 * t1i)], w3 = twl[PD(3 * t1i)];
    #pragma unroll
    for (int m = 0; m < 2; ++m) {
      float2* sm = s[m];
      float2 u0 = sm[PD(base)];
      float2 u1 = cmulcf(sm[PD(base + q)],     w1);
      float2 u2 = cmulcf(sm[PD(base + 2 * q)], w2);
      float2 u3 = cmulcf(sm[PD(base + 3 * q)], w3);
      float2 t0 = make_float2(u0.x + u2.x, u0.y + u2.y);
      float2 t1 = make_float2(u0.x - u2.x, u0.y - u2.y);
      float2 t2 = make_float2(u1.x + u3.x, u1.y + u3.y);
      float2 t3 = make_float2(u1.x - u3.x, u1.y - u3.y);
      sm[PD(base)]         = make_float2(t0.x + t2.x, t0.y + t2.y);
      sm[PD(base + 2 * q)] = make_float2(t0.x - t2.x, t0.y - t2.y);
      sm[PD(base + q)]     = make_float2(t1.x - t3.y, t1.y + t3.x);
      sm[PD(base + 3 * q)] = make_float2(t1.x + t3.y, t1.y - t3.x);
    }
    __syncthreads();
  }
  #pragma unroll
  for (int m = 0; m < 2; ++m) {
    float4* rp = (float4*)(row0 + (size_t)m * NRHO);
    for (int e = tid; e < 512; e += 256) {
      float2 a = s[m][PD(2 * e)], b = s[m][PD(2 * e + 1)];
      rp[e] = make_float4(a.x, a.y, b.x, b.y);
    }
  }
}

// ---------------- paired Hermitian irfft(512): 8 rho-rows = 4 complex IFFTs ----------------
// Inverse DIF (sign +), natural in -> bit-reversed out. Stages (8,7),(6,5),(4,3),(2,1)
// fused as radix-4 in registers (odd-pair twiddle conj(-i*w) = +i*conj(w), free
// rotation), then single radix-2 stage lh=0. Only theta rows 128..383 written,
// COMPACTED (row j-128) and in natural theta order.
__global__ __launch_bounds__(256) void k_irfft_th(const float2* __restrict__ T,
                                                  const float2* __restrict__ tw1024f,
                                                  float* __restrict__ gkT) {
  __shared__ float2 s[4][S4];
  __shared__ float2 twl[256];
  const int i0   = blockIdx.x * 8;
  const int lb   = blockIdx.y;
  const int span = blockIdx.z;
  const int tid  = threadIdx.x;
  twl[tid] = tw1024f[2 * tid];
  const float2* Tb = T + (size_t)(span * gridDim.y + lb) * (ZROWS * NRHO);
  __syncthreads();
  // stage A: raw F -> LDS (pair m holds F0 at SW(k), F1 at SW(256+k))
  for (int it = 0; it < 8; ++it) {
    int e = tid + (it << 8);
    int k = e >> 3, rr = e & 7;
    int m = rr >> 1, p = rr & 1;
    s[m][SW(k + 256 * p)] = Tb[(size_t)k * NRHO + i0 + rr];
  }
  __syncthreads();
  // stage B: build Z = F0 + i*F1 over k=0..511 (registers to avoid in-place hazard)
  float2 Zr[8];
  for (int it = 0; it < 8; ++it) {
    int e = tid + (it << 8);
    int m = e >> 9, k = e & 511;
    float2 z;
    if (k == 256) z = make_float2(0.f, 0.f);
    else {
      int k2 = (k < 256) ? k : 512 - k;
      float2 F0 = s[m][SW(k2)];
      float2 F1 = s[m][SW(256 + k2)];
      if (k2 == 0) { F0.y = 0.f; F1.y = 0.f; }       // numpy irfft ignores DC imag
      if (k < 256) z = make_float2(F0.x - F1.y, F0.y + F1.x);
      else         z = make_float2(F0.x + F1.y, F1.x - F0.y);
    }
    Zr[it] = z;
  }
  __syncthreads();
  for (int it = 0; it < 8; ++it) {
    int e = tid + (it << 8);
    int m = e >> 9, k = e & 511;
    s[m][SW(k)] = Zr[it];
  }
  // fused inverse DIF pairs (8,7),(6,5),(4,3),(2,1)
  #pragma unroll
  for (int lh = 8; lh >= 2; lh -= 2) {
    __syncthreads();
    const int h = 1 << (lh - 1);                     // half of stage-lh span
    #pragma unroll
    for (int it = 0; it < 2; ++it) {
      int e = tid + (it << 8);                       // 0..511
      int m = e >> 7, gq = e & 127;
      int pos = gq & (h - 1);
      int base = ((gq >> (lh - 1)) << (lh + 1)) | pos;
      float2 wa = twl[pos << (8 - lh)];
      float2 w2 = twl[pos << (9 - lh)];
      float2* sm = s[m];
      float2 a = sm[SW(base)];
      float2 b = sm[SW(base + h)];
      float2 c = sm[SW(base + 2 * h)];
      float2 d = sm[SW(base + 3 * h)];
      // stage lh (span 2h): pairs (a,c),(b,d); odd-pair w = -i*wa -> conj mult by +i
      float2 ap = make_float2(a.x + c.x, a.y + c.y);
      float2 cp = cmulcf(make_float2(a.x - c.x, a.y - c.y), wa);
      float2 bp = make_float2(b.x + d.x, b.y + d.y);
      float2 tt = cmulcf(make_float2(b.x - d.x, b.y - d.y), wa);
      float2 dp = make_float2(-tt.y, tt.x);          // (+i)*cmulcf(b-d, wa)
      // stage lh-1 (span h): pairs (ap,bp),(cp,dp), same w2
      sm[SW(base)]         = make_float2(ap.x + bp.x, ap.y + bp.y);
      sm[SW(base + h)]     = cmulcf(make_float2(ap.x - bp.x, ap.y - bp.y), w2);
      sm[SW(base + 2 * h)] = make_float2(cp.x + dp.x, cp.y + dp.y);
      sm[SW(base + 3 * h)] = cmulcf(make_float2(cp.x - dp.x, cp.y - dp.y), w2);
    }
  }
  // final radix-2 stage lh=0 (w = twl[0] = 1)
  __syncthreads();
  #pragma unroll
  for (int it = 0; it < 4; ++it) {
    int e = tid + (it << 8);
    int m = e >> 8, b = e & 255;
    int ia = b << 1;
    float2* sm = s[m];
    float2 u = sm[SW(ia)];
    float2 v = sm[SW(ia + 1)];
    sm[SW(ia)]     = make_float2(u.x + v.x, u.y + v.y);
    sm[SW(ia + 1)] = make_float2(u.x - v.x, u.y - v.y);
  }
  __syncthreads();
  // write ONLY theta rows 128..383, compacted+natural order (2048 values)
  float* gb = gkT + (size_t)(span * gridDim.y + lb) * (GROWS * NRHO);
  for (int it = 0; it < 8; ++it) {
    int e = tid + (it << 8);                         // 0..2047
    int ro = e >> 3, rr = e & 7;                     // ro = j-128
    int j = ro + 128;
    int jslot = __brev((unsigned)j) >> 23;           // DIF output slot of theta j
    float2 z = s[rr >> 1][SW(jslot)];
    gb[(size_t)ro * NRHO + i0 + rr] = (rr & 1) ? z.y : z.x;
  }
}

// ---------------- resample to (angle, det), ALL spans in one dispatch ----------------
// Span of angle t: k = (3t)>>10 (exact partition; boundaries never integral).
// gkT rows are compacted: row = fx - 128 (fx proven in [128,384)).
__global__ __launch_bounds__(256) void k_scatter(const float* __restrict__ gkT,
                                                 float* __restrict__ out,
                                                 int b0, int chunk,
                                                 double d_rho, double aR) {
  int p = blockIdx.x * 256 + threadIdx.x;
  if (p >= PTOT) return;
  const int t = p >> 9;
  const int d = p & 511;
  const int span = (3 * t) >> 10;
  const double beta = M_PI / 3.0;
  double th0 = (double)t * M_PI / 1024.0 - beta / 2.0;
  double th00 = th0 - (double)span * beta;
  double d_th = 2.0 * beta / 512.0;
  double th_lp0 = -256.0 * d_th, th_lpL = 255.0 * d_th;
  double p1 = (th00 - th_lp0) / (th_lpL - th_lp0) * 511.0;
  double s0v = (d == 511) ? 1.0 : (double)d * (2.0 / 511.0) - 1.0;
  double p2 = log(s0v * aR + (1.0 - aR) * cos(th00));
  double rho0 = -1024.0 * d_rho, rhoL = -1.0 * d_rho;
  p2 = (p2 - rho0) / (rhoL - rho0) * 1023.0;
  double fy = floor(p2); fy = fy < 0.0 ? 0.0 : (fy > 1022.0 ? 1022.0 : fy);
  double fx = floor(p1); fx = fx < 0.0 ? 0.0 : (fx > 510.0 ? 510.0 : fx);
  int idx = ((int)fx - 128) * 1024 + (int)fy;        // compacted natural-order row
  const float* gsp = gkT + (size_t)span * chunk * (GROWS * NRHO);
  for (int lb = 0; lb < chunk; ++lb)
    out[(size_t)(b0 + lb) * PTOT + p] = gsp[(size_t)lb * (GROWS * NRHO) + idx];
}

// ---------------- launch ----------------
extern "C" void kernel_launch(void* const* d_in, const int* in_sizes, int n_in,
                              void* d_out, int out_size, void* d_ws, size_t ws_size,
                              hipStream_t stream) {
  (void)n_in; (void)out_size;
  const float* x = (const float*)d_in[0];
  float* out = (float*)d_out;
  const int batch = in_sizes[0] / (NIMG * NIMG);

  const size_t zeta_b = (size_t)ZROWS * NRHO * sizeof(float2);          // 2 MB
  const size_t idx_b  = (size_t)NSPAN * NRHO * NTH * sizeof(int);       // 6 MB
  const size_t tab_b  = 2048 * sizeof(double) * 2 + 1024 * sizeof(float2) * 2;
  const size_t per_b  = (size_t)NSPAN * ((size_t)ZROWS * NRHO * sizeof(float2)
                      + (size_t)GROWS * NRHO * sizeof(float));          // 9 MB / image
  int chunk = batch;
  while (chunk > 1 && zeta_b + idx_b + tab_b + (size_t)chunk * per_b > ws_size) chunk >>= 1;

  char* ws = (char*)d_ws;
  float2* zetaT   = (float2*)ws;  ws += zeta_b;
  int*    idx1    = (int*)ws;     ws += idx_b;
  double* Ltab    = (double*)ws;  ws += 2048 * sizeof(double);
  double* amp     = (double*)ws;  ws += 2048 * sizeof(double);
  float2* tw1024f = (float2*)ws;  ws += 1024 * sizeof(float2);
  float2* tw2048f = (float2*)ws;  ws += 1024 * sizeof(float2);
  float2* T       = (float2*)ws;  ws += (size_t)NSPAN * chunk * ZROWS * NRHO * sizeof(float2);
  float*  gkT     = (float*)ws;

  k_pre     <<<dim3(8),    dim3(256), 0, stream>>>(Ltab, amp, tw1024f, tw2048f);
  k_zeta    <<<dim3(1024), dim3(256), 0, stream>>>(Ltab, amp, tw2048f, zetaT,
                                                   g_C.G_LA, g_C.dth, g_C.constv);
  k_idx_lp2c<<<dim3((NSPAN * NRHO * NTH) / 256), dim3(256), 0, stream>>>(idx1, g_C.d_rho, g_C.aR);

  for (int b0 = 0; b0 < batch; b0 += chunk) {
    int c = (b0 + chunk <= batch) ? chunk : (batch - b0);
    k_gather_rfft<<<dim3(NRHO / 8, c, NSPAN), dim3(256), 0, stream>>>(x, idx1, tw1024f, T, b0, g_C.d_rho);
    k_fft_rho    <<<dim3(ZROWS / 2, c, NSPAN), dim3(256), 0, stream>>>(T, zetaT, tw1024f);
    k_irfft_th   <<<dim3(NRHO / 8, c, NSPAN), dim3(256), 0, stream>>>(T, tw1024f, gkT);
    k_scatter    <<<dim3(PTOT / 256), dim3(256), 0, stream>>>(gkT, out, b0, c,
                                                              g_C.d_rho, g_C.aR);
  }
}

// Round 4
// 262.426 us; speedup vs baseline: 1.0955x; 1.0818x over previous
//
#include <hip/hip_runtime.h>
#include <cmath>

#ifndef M_PI
#define M_PI 3.14159265358979323846
#endif

#define NIMG 512
#define NRHO 1024
#define NTH  512
#define ZROWS 256           // theta bins kept (bin 256 zeroed by zeta -> dropped)
#define GROWS 256           // gk theta rows kept: fx in [128,384) only
#define S4   520            // LDS row stride (float2) for 4-row pair kernels
#define PTOT (1024*512)     // n_angles * n_det
#define NSPAN 3

// ---------------- host-side scalar constants ----------------
struct Consts { double G_LA, d_rho, aR, dth, constv; };

static Consts compute_consts() {
  Consts c;
  const double beta = M_PI / 3.0;
  const double sb = sin(beta / 2.0), cb = cos(beta / 2.0);
  const double aR = sb / (1.0 + sb);
  const double am = (cb - sb) / (1.0 + sb);
  double g = -1e300;
  const double start = -M_PI / 2.0, stop = M_PI / 2.0;
  const double delta = (stop - start) / 999.0;
  for (int i = 0; i < 1000; ++i) {
    double t = (i == 999) ? stop : (double)i * delta + start;
    double wre = aR * cos(t) + (1.0 - aR);
    double wim = aR * sin(t);
    double v = log(hypot(wre, wim)) + log(cos(beta / 2.0 - atan2(wim, wre)));
    if (!std::isnan(v) && v > g) g = v;
  }
  c.aR    = aR;
  c.G_LA  = g - log(am);
  c.d_rho = c.G_LA / 1024.0;
  double t1 = (-1023.0 / 2048.0) * beta * 2.0;
  double t0 = (-1024.0 / 2048.0) * beta * 2.0;
  c.dth = t1 - t0;
  c.constv = sqrt(0.5) * M_PI / 4.0 / aR / sqrt(2.0);
  return c;
}
static const Consts g_C = compute_consts();

// ---------------- device helpers ----------------
__device__ __forceinline__ float2 cmulf(float2 a, float2 b) {
  return make_float2(a.x * b.x - a.y * b.y, a.x * b.y + a.y * b.x);
}
__device__ __forceinline__ float2 cmulcf(float2 a, float2 w) {   // a * conj(w)
  return make_float2(a.x * w.x + a.y * w.y, a.y * w.x - a.x * w.y);
}
__device__ __forceinline__ int SW(int i) { return i ^ ((i >> 5) & 31); }  // XOR bank swizzle
__device__ __forceinline__ int PD(int i) { return i + (i >> 4); }         // pad-per-16 permutation
__device__ __forceinline__ int dr4_10(int v) {                    // reverse 5 base-4 digits
  int r = 0;
  #pragma unroll
  for (int k = 0; k < 5; ++k) { r = (r << 2) | (v & 3); v >>= 2; }
  return r;
}
// forward DIF radix-4 butterfly (inputs at digits 0..3, outputs pre-twiddle)
__device__ __forceinline__ void bf4f(float2 a, float2 b, float2 c, float2 d,
                                     float2& y0, float2& y1, float2& y2, float2& y3) {
  float2 A = make_float2(a.x + c.x, a.y + c.y);
  float2 C = make_float2(a.x - c.x, a.y - c.y);
  float2 B = make_float2(b.x + d.x, b.y + d.y);
  float2 D = make_float2(b.x - d.x, b.y - d.y);
  y0 = make_float2(A.x + B.x, A.y + B.y);
  y2 = make_float2(A.x - B.x, A.y - B.y);
  y1 = make_float2(C.x + D.y, C.y - D.x);   // C - iD
  y3 = make_float2(C.x - D.y, C.y + D.x);   // C + iD
}
// inverse DIT radix-4 butterfly (inputs already conj-twiddled)
__device__ __forceinline__ void bf4i(float2 u0, float2 u1, float2 u2, float2 u3,
                                     float2& z0, float2& z1, float2& z2, float2& z3) {
  float2 t0 = make_float2(u0.x + u2.x, u0.y + u2.y);
  float2 t1 = make_float2(u0.x - u2.x, u0.y - u2.y);
  float2 t2 = make_float2(u1.x + u3.x, u1.y + u3.y);
  float2 t3 = make_float2(u1.x - u3.x, u1.y - u3.y);
  z0 = make_float2(t0.x + t2.x, t0.y + t2.y);
  z2 = make_float2(t0.x - t2.x, t0.y - t2.y);
  z1 = make_float2(t1.x - t3.y, t1.y + t3.x);   // t1 + i t3
  z3 = make_float2(t1.x + t3.y, t1.y - t3.x);   // t1 - i t3
}
__device__ __forceinline__ double h_val(int jj) {
  const double ctab[11] = {-216254335.0, 679543284.0, -1412947389.0, 2415881496.0,
                           -3103579086.0, 2939942400.0, -2023224114.0, 984515304.0,
                           -321455811.0, 63253516.0, -5675265.0};
  int j = -1;
  if (jj <= 10) j = jj;
  else if (jj >= 2038) j = 2048 - jj;
  if (j < 0) return 1.0;
  double c = 1.0 + ctab[j] / 958003200.0;
  if (j == 0) c = 2.0 * (c - 0.5);
  return c;
}

// ---------------- precompute: L/amp tables + fp32 twiddle tables ----------------
__global__ __launch_bounds__(256) void k_pre(double* __restrict__ Ltab,
                                             double* __restrict__ amp,
                                             float2* __restrict__ tw1024f,
                                             float2* __restrict__ tw2048f) {
  int id = blockIdx.x * 256 + threadIdx.x;
  const double beta = M_PI / 3.0;
  if (id < 2048) {
    double th = ((double)(id - 1024) / 2048.0) * beta * 2.0;
    double L = log(cos(th));
    Ltab[id] = L;
    amp[id]  = h_val(id) * exp(-L);
  }
  if (id < 1024) {
    double a1 = -2.0 * M_PI * (double)id / 1024.0;
    double a2 = -2.0 * M_PI * (double)id / 2048.0;
    double s1, c1, s2, c2;
    sincos(a1, &s1, &c1); sincos(a2, &s2, &c2);
    tw1024f[id] = make_float2((float)c1, (float)s1);
    tw2048f[id] = make_float2((float)c2, (float)s2);
  }
}

// ---------------- zeta: fp32 2048-pt FFT per rho-frequency row ----------------
// zetaT[j][pp], j<256 theta bin; pp = PERM(dr4_10(rho freq)) where
// PERM(p) = ((p&15)<<6)|(p>>4) matches k_fft_rho's middle-pass coalesced read.
// Includes const*dth/b3 and both inverse-FFT normalizations.
__global__ __launch_bounds__(256) void k_zeta(const double* __restrict__ Ltab,
                                              const double* __restrict__ amp,
                                              const float2* __restrict__ tw2048f,
                                              float2* __restrict__ zetaT,
                                              double G_LA, double dth, double constv) {
  __shared__ float2 s[2048 + 128];
  __shared__ float2 twl[1024 + 64];
  const int i   = blockIdx.x;    // k_rho row 0..1023
  const int tid = threadIdx.x;
  for (int e = tid; e < 1024; e += 256) twl[PD(e)] = tw2048f[e];
  const double om = 2.0 * M_PI * (double)(i - 512) / G_LA;
  const double INV2PI = 1.0 / (2.0 * M_PI);
  for (int j = tid; j < 2048; j += 256) {
    int jj = (j + 1024) & 2047;
    double ph = -om * Ltab[jj] * INV2PI;
    ph -= floor(ph);
    float ang = (float)ph * 6.28318530717958647f;
    float sv, cv; __sincosf(ang, &sv, &cv);
    float a = (float)amp[jj];
    s[PD(__brev((unsigned)j) >> 21)] = make_float2(a * cv, a * sv);
  }
  for (int lh = 0; lh < 11; ++lh) {
    __syncthreads();
    for (int e = tid; e < 1024; e += 256) {
      int pos = e & ((1 << lh) - 1);
      int ia  = ((e >> lh) << (lh + 1)) | pos;
      float2 w = twl[PD(pos << (10 - lh))];
      float2 u = s[PD(ia)];
      float2 v = cmulf(s[PD(ia + (1 << lh))], w);
      s[PD(ia)]             = make_float2(u.x + v.x, u.y + v.y);
      s[PD(ia + (1 << lh))] = make_float2(u.x - v.x, u.y - v.y);
    }
  }
  __syncthreads();
  const int i2 = (i + 512) & 1023;
  const int p  = dr4_10(i2);
  const int pp = ((p & 15) << 6) | (p >> 4);          // middle-pass coalescing permute
  const double b3r = (4.0 + 2.0 * cos(2.0 * M_PI * (double)i2 / 1024.0)) / 6.0;
  if (tid < 256) {
    int j2 = tid;
    float2 z = make_float2(0.f, 0.f);
    if (i != 0) {
      float2 F = s[PD(j2)];
      double b3t = (4.0 + 2.0 * cos(2.0 * M_PI * (double)j2 / 512.0)) / 6.0;
      double sc = dth * constv / (b3r * b3t) * (1.0 / (1024.0 * 512.0));
      z = make_float2((float)((double)F.x * sc), (float)((double)F.y * sc));
    }
    zetaT[(size_t)j2 * 1024 + pp] = z;
  }
}

// ---------------- gather index map, ALL spans, natural theta order ----------------
__global__ __launch_bounds__(256) void k_idx_lp2c(int* __restrict__ idx1,
                                                  double d_rho, double aR) {
  int q = blockIdx.x * 256 + threadIdx.x;
  int span = q >> 19;                                // q / (NRHO*NTH)
  int ql = q & (NRHO * NTH - 1);
  int i = ql >> 9, j = ql & 511;
  const double beta = M_PI / 3.0;
  double d_th = 2.0 * beta / 512.0;
  double th = (double)(j - 256) * d_th;
  double er = exp((double)(i - 1024) * d_rho);
  double t1 = er * cos(th), t2 = er * sin(th);
  double a = (double)span * beta + beta / 2.0;
  double ca = cos(a), sa = sin(a);
  double l1 = ((t1 - (1.0 - aR)) * ca - t2 * sa) / aR;
  double l2 = -(((t1 - (1.0 - aR)) * sa + t2 * ca) / aR);
  l1 = (l1 + 1.0) / 2.0 * 511.0;
  l2 = (l2 + 1.0) / 2.0 * 511.0;
  double fy = floor(l1); fy = fy < 0.0 ? 0.0 : (fy > 510.0 ? 510.0 : fy);
  double fx = floor(l2); fx = fx < 0.0 ? 0.0 : (fx > 510.0 ? 510.0 : fx);
  idx1[q] = (int)fy * 512 + (int)fx;
}

// ---------------- gather + paired rfft(512): 8 rho-rows = 4 complex FFTs ----------------
// Forward DIT, input bit-reversed. Stages 0..7 fused as radix-4 (two radix-2 levels
// in registers; odd-pair twiddle of second level is -i*w2, a free rotation), then
// one radix-2 stage lh=8. 5 barriers / 40 LDS accesses per thread vs 9 / 72.
__global__ __launch_bounds__(256) void k_gather_rfft(const float* __restrict__ x,
                                                     const int* __restrict__ idx1,
                                                     const float2* __restrict__ tw1024f,
                                                     float2* __restrict__ T,
                                                     int b0, double d_rho) {
  __shared__ float2 s[4][S4];     // 16.6 KB
  __shared__ float2 twl[256];
  const int bx   = blockIdx.x;
  const int g    = ((bx & 7) << 4) | (bx >> 3);      // XCD ring swizzle (128 blocks)
  const int i0   = g * 8;
  const int lb   = blockIdx.y;
  const int span = blockIdx.z;
  const int tid  = threadIdx.x;
  twl[tid] = tw1024f[2 * tid];                       // exp(-2pi i m/512), m<256
  const int r  = tid >> 5;                           // rho row 0..7
  const int t5 = tid & 31;
  const float er = (float)exp((double)(i0 + r - 1024) * d_rho);
  const float* xb = x + (size_t)(b0 + lb) * (NIMG * NIMG);
  const int4* ip = (const int4*)(idx1 + span * (NRHO * NTH) + (i0 + r) * 512 + t5 * 16);
  int4 i4[4];
  #pragma unroll
  for (int u = 0; u < 4; ++u) i4[u] = ip[u];
  float v[16];
  #pragma unroll
  for (int u = 0; u < 4; ++u) {                      // 16 gathers issued back-to-back
    v[4 * u + 0] = xb[i4[u].x];
    v[4 * u + 1] = xb[i4[u].y];
    v[4 * u + 2] = xb[i4[u].z];
    v[4 * u + 3] = xb[i4[u].w];
  }
  float* sm = (float*)s[r >> 1];
  const int p = r & 1;
  #pragma unroll
  for (int u = 0; u < 16; ++u) {
    int j = t5 * 16 + u;
    int slot = __brev((unsigned)j) >> 23;            // bit-reversal for free
    sm[2 * SW(slot) + p] = v[u] * er;
  }
  // fused radix-4 stages (0,1),(2,3),(4,5),(6,7)
  #pragma unroll
  for (int lh = 0; lh < 8; lh += 2) {
    __syncthreads();
    const int q = 1 << lh;
    #pragma unroll
    for (int it = 0; it < 2; ++it) {
      int e = tid + (it << 8);                       // 0..511
      int m = e >> 7, gq = e & 127;
      int pos = gq & (q - 1);
      int base = ((gq >> lh) << (lh + 2)) | pos;
      float2 w1 = twl[pos << (8 - lh)];
      float2 w2 = twl[pos << (7 - lh)];
      float2* smm = s[m];
      float2 a = smm[SW(base)];
      float2 b = smm[SW(base + q)];
      float2 c = smm[SW(base + 2 * q)];
      float2 d = smm[SW(base + 3 * q)];
      float2 wb = cmulf(b, w1), wd = cmulf(d, w1);
      float2 t0 = make_float2(a.x + wb.x, a.y + wb.y);
      float2 t1 = make_float2(a.x - wb.x, a.y - wb.y);
      float2 t2 = make_float2(c.x + wd.x, c.y + wd.y);
      float2 t3 = make_float2(c.x - wd.x, c.y - wd.y);
      float2 z2 = cmulf(t2, w2);
      float2 p3 = cmulf(t3, w2);
      float2 z3 = make_float2(p3.y, -p3.x);          // (-i)*(w2*t3)
      smm[SW(base)]         = make_float2(t0.x + z2.x, t0.y + z2.y);
      smm[SW(base + 2 * q)] = make_float2(t0.x - z2.x, t0.y - z2.y);
      smm[SW(base + q)]     = make_float2(t1.x + z3.x, t1.y + z3.y);
      smm[SW(base + 3 * q)] = make_float2(t1.x - z3.x, t1.y - z3.y);
    }
  }
  // final radix-2 stage lh=8
  __syncthreads();
  #pragma unroll
  for (int it = 0; it < 4; ++it) {
    int e = tid + (it << 8);
    int m = e >> 8, b = e & 255;                     // pos=b, ia=b
    float2 w = twl[b];
    float2* smm = s[m];
    float2 u = smm[SW(b)];
    float2 vv = cmulf(smm[SW(b + 256)], w);
    smm[SW(b)]       = make_float2(u.x + vv.x, u.y + vv.y);
    smm[SW(b + 256)] = make_float2(u.x - vv.x, u.y - vv.y);
  }
  __syncthreads();
  // unpack pair spectra + transposed coalesced write (64B per theta bin)
  float2* Tb = T + (size_t)(span * gridDim.y + lb) * (ZROWS * NRHO);
  for (int it = 0; it < 8; ++it) {
    int e = tid + (it << 8);                         // 0..2047
    int k = e >> 3, rr = e & 7;
    int m = rr >> 1, pp = rr & 1;
    float2 Z  = s[m][SW(k)];
    float2 Zc = s[m][SW((512 - k) & 511)];
    float2 F;
    if (!pp) F = make_float2(0.5f * (Z.x + Zc.x), 0.5f * (Z.y - Zc.y));
    else     F = make_float2(0.5f * (Z.y + Zc.y), 0.5f * (Zc.x - Z.x));
    Tb[(size_t)k * NRHO + i0 + rr] = F;
  }
}

// ---------------- rho: fft1024 * zeta * ifft1024, register radix-16, 4 bins/block ----
// Each thread owns 16 points r[c][a] = row[t6 + 64a + 256c] of ONE bin (64 thr/bin).
// Stage plan (radix-4 DIF lq=8,6,4,2,0 / DIT lq=0,2,4,6,8 — identical semantics to
// the 5-stage loop version, pairs fused in registers):
//   fwd(8,6) from GLOBAL -> LDS; fwd(4,2) LDS round-trip;
//   [fwd(0) + zeta + inv(0)] one LDS round-trip (zeta pre-permuted by k_zeta);
//   inv(2,4) LDS round-trip; inv(6,8) LDS -> GLOBAL.
// 4 LDS round-trips / 5 barriers vs 11 round-trips / 11 barriers.
__global__ __launch_bounds__(256) void k_fft_rho(float2* __restrict__ T,
                                                 const float2* __restrict__ zetaT,
                                                 const float2* __restrict__ tw1024f) {
  __shared__ float2 s[4][1024 + 64];
  __shared__ float2 twl[1024 + 64];
  const int j0   = blockIdx.x * 4;                   // four theta bins per block
  const int lb   = blockIdx.y;
  const int span = blockIdx.z;
  const int tid  = threadIdx.x;
  const int bin  = tid >> 6;
  const int t6   = tid & 63;
  float2* rowb = T + ((size_t)(span * gridDim.y + lb) * ZROWS + j0 + bin) * NRHO;

  // global load, coalesced 512B per (a,c): r[c][a] = rowb[t6 + 64a + 256c]
  float2 r[4][4];
  #pragma unroll
  for (int c = 0; c < 4; ++c)
    #pragma unroll
    for (int a = 0; a < 4; ++a)
      r[c][a] = rowb[t6 + 64 * a + 256 * c];

  for (int e = tid; e < 1024; e += 256) twl[PD(e)] = tw1024f[e];
  __syncthreads();

  // ---- fwd fused (lq=8 then lq=6) in registers
  #pragma unroll
  for (int a = 0; a < 4; ++a) {                      // lq=8: over c, jj = t6+64a, tfac=1
    int jj = t6 + 64 * a;
    float2 y0, y1, y2, y3;
    bf4f(r[0][a], r[1][a], r[2][a], r[3][a], y0, y1, y2, y3);
    r[0][a] = y0;
    r[1][a] = cmulf(y1, twl[PD(jj)]);
    r[2][a] = cmulf(y2, twl[PD(2 * jj)]);
    r[3][a] = cmulf(y3, twl[PD(3 * jj)]);
  }
  {                                                  // lq=6: over a, jj = t6, tfac=4
    float2 w1 = twl[PD(4 * t6)], w2 = twl[PD(8 * t6)], w3 = twl[PD(12 * t6)];
    #pragma unroll
    for (int c = 0; c < 4; ++c) {
      float2 y0, y1, y2, y3;
      bf4f(r[c][0], r[c][1], r[c][2], r[c][3], y0, y1, y2, y3);
      r[c][0] = y0; r[c][1] = cmulf(y1, w1); r[c][2] = cmulf(y2, w2); r[c][3] = cmulf(y3, w3);
    }
  }
  #pragma unroll
  for (int c = 0; c < 4; ++c)
    #pragma unroll
    for (int a = 0; a < 4; ++a)
      s[bin][PD(t6 + 64 * a + 256 * c)] = r[c][a];
  __syncthreads();

  // ---- fwd fused (lq=4 then lq=2): set {64*B64 + b2 + 4a + 16c}
  const int B64 = t6 >> 2, b2 = t6 & 3;
  const int fbase = 64 * B64 + b2;
  #pragma unroll
  for (int c = 0; c < 4; ++c)
    #pragma unroll
    for (int a = 0; a < 4; ++a)
      r[c][a] = s[bin][PD(fbase + 4 * a + 16 * c)];
  #pragma unroll
  for (int a = 0; a < 4; ++a) {                      // lq=4: over c, jj = b2+4a, tfac=16
    int ji = 16 * (b2 + 4 * a);
    float2 y0, y1, y2, y3;
    bf4f(r[0][a], r[1][a], r[2][a], r[3][a], y0, y1, y2, y3);
    r[0][a] = y0;
    r[1][a] = cmulf(y1, twl[PD(ji)]);
    r[2][a] = cmulf(y2, twl[PD(2 * ji)]);
    r[3][a] = cmulf(y3, twl[PD(3 * ji)]);
  }
  {                                                  // lq=2: over a, jj = b2, tfac=64
    float2 w1 = twl[PD(64 * b2)], w2 = twl[PD(128 * b2)], w3 = twl[PD(192 * b2)];
    #pragma unroll
    for (int c = 0; c < 4; ++c) {
      float2 y0, y1, y2, y3;
      bf4f(r[c][0], r[c][1], r[c][2], r[c][3], y0, y1, y2, y3);
      r[c][0] = y0; r[c][1] = cmulf(y1, w1); r[c][2] = cmulf(y2, w2); r[c][3] = cmulf(y3, w3);
    }
  }
  #pragma unroll
  for (int c = 0; c < 4; ++c)
    #pragma unroll
    for (int a = 0; a < 4; ++a)
      s[bin][PD(fbase + 4 * a + 16 * c)] = r[c][a];
  __syncthreads();

  // ---- middle: fwd lq=0 + zeta + inv lq=0 on 4 consecutive quads {16*t6 + 4u + v}
  {
    const float2* zp = zetaT + (size_t)(j0 + bin) * NRHO;   // PERMUTED rows (k_zeta)
    #pragma unroll
    for (int u = 0; u < 4; ++u) {
      int o0 = 16 * t6 + 4 * u;
      float2 a0 = s[bin][PD(o0)],     a1 = s[bin][PD(o0 + 1)];
      float2 a2 = s[bin][PD(o0 + 2)], a3 = s[bin][PD(o0 + 3)];
      float2 y0, y1, y2, y3;
      bf4f(a0, a1, a2, a3, y0, y1, y2, y3);
      float2 q0 = zp[64 * (4 * u + 0) + t6];         // coalesced: lanes t6 consecutive
      float2 q1 = zp[64 * (4 * u + 1) + t6];
      float2 q2 = zp[64 * (4 * u + 2) + t6];
      float2 q3 = zp[64 * (4 * u + 3) + t6];
      y0 = cmulf(y0, q0); y1 = cmulf(y1, q1); y2 = cmulf(y2, q2); y3 = cmulf(y3, q3);
      float2 z0, z1, z2, z3;
      bf4i(y0, y1, y2, y3, z0, z1, z2, z3);          // inv lq=0, w=1
      s[bin][PD(o0)]     = z0; s[bin][PD(o0 + 1)] = z1;
      s[bin][PD(o0 + 2)] = z2; s[bin][PD(o0 + 3)] = z3;
    }
  }
  __syncthreads();

  // ---- inv fused (lq=2 then lq=4): set {64*B64 + b2 + 4a + 16c}
  #pragma unroll
  for (int c = 0; c < 4; ++c)
    #pragma unroll
    for (int a = 0; a < 4; ++a)
      r[c][a] = s[bin][PD(fbase + 4 * a + 16 * c)];
  {                                                  // lq=2: over a, jj = b2, tfac=64
    float2 w1 = twl[PD(64 * b2)], w2 = twl[PD(128 * b2)], w3 = twl[PD(192 * b2)];
    #pragma unroll
    for (int c = 0; c < 4; ++c) {
      float2 u1 = cmulcf(r[c][1], w1);
      float2 u2 = cmulcf(r[c][2], w2);
      float2 u3 = cmulcf(r[c][3], w3);
      bf4i(r[c][0], u1, u2, u3, r[c][0], r[c][1], r[c][2], r[c][3]);
    }
  }
  #pragma unroll
  for (int a = 0; a < 4; ++a) {                      // lq=4: over c, jj = b2+4a, tfac=16
    int ji = 16 * (b2 + 4 * a);
    float2 u1 = cmulcf(r[1][a], twl[PD(ji)]);
    float2 u2 = cmulcf(r[2][a], twl[PD(2 * ji)]);
    float2 u3 = cmulcf(r[3][a], twl[PD(3 * ji)]);
    bf4i(r[0][a], u1, u2, u3, r[0][a], r[1][a], r[2][a], r[3][a]);
  }
  #pragma unroll
  for (int c = 0; c < 4; ++c)
    #pragma unroll
    for (int a = 0; a < 4; ++a)
      s[bin][PD(fbase + 4 * a + 16 * c)] = r[c][a];
  __syncthreads();

  // ---- inv fused (lq=6 then lq=8): set {t6 + 64a + 256c}, write straight to global
  #pragma unroll
  for (int c = 0; c < 4; ++c)
    #pragma unroll
    for (int a = 0; a < 4; ++a)
      r[c][a] = s[bin][PD(t6 + 64 * a + 256 * c)];
  {                                                  // lq=6: over a, jj = t6, tfac=4
    float2 w1 = twl[PD(4 * t6)], w2 = twl[PD(8 * t6)], w3 = twl[PD(12 * t6)];
    #pragma unroll
    for (int c = 0; c < 4; ++c) {
      float2 u1 = cmulcf(r[c][1], w1);
      float2 u2 = cmulcf(r[c][2], w2);
      float2 u3 = cmulcf(r[c][3], w3);
      bf4i(r[c][0], u1, u2, u3, r[c][0], r[c][1], r[c][2], r[c][3]);
    }
  }
  #pragma unroll
  for (int a = 0; a < 4; ++a) {                      // lq=8: over c, jj = t6+64a, tfac=1
    int jj = t6 + 64 * a;
    float2 u1 = cmulcf(r[1][a], twl[PD(jj)]);
    float2 u2 = cmulcf(r[2][a], twl[PD(2 * jj)]);
    float2 u3 = cmulcf(r[3][a], twl[PD(3 * jj)]);
    bf4i(r[0][a], u1, u2, u3, r[0][a], r[1][a], r[2][a], r[3][a]);
  }
  #pragma unroll
  for (int c = 0; c < 4; ++c)
    #pragma unroll
    for (int a = 0; a < 4; ++a)
      rowb[t6 + 64 * a + 256 * c] = r[c][a];
}

// ---------------- paired Hermitian irfft(512): 8 rho-rows = 4 complex IFFTs ----------------
// Inverse DIF (sign +), natural in -> bit-reversed out. Stages (8,7),(6,5),(4,3),(2,1)
// fused as radix-4 in registers (odd-pair twiddle conj(-i*w) = +i*conj(w), free
// rotation), then single radix-2 stage lh=0. Only theta rows 128..383 written,
// COMPACTED (row j-128) and in natural theta order.
__global__ __launch_bounds__(256) void k_irfft_th(const float2* __restrict__ T,
                                                  const float2* __restrict__ tw1024f,
                                                  float* __restrict__ gkT) {
  __shared__ float2 s[4][S4];
  __shared__ float2 twl[256];
  const int i0   = blockIdx.x * 8;
  const int lb   = blockIdx.y;
  const int span = blockIdx.z;
  const int tid  = threadIdx.x;
  twl[tid] = tw1024f[2 * tid];
  const float2* Tb = T + (size_t)(span * gridDim.y + lb) * (ZROWS * NRHO);
  __syncthreads();
  // stage A: raw F -> LDS (pair m holds F0 at SW(k), F1 at SW(256+k))
  for (int it = 0; it < 8; ++it) {
    int e = tid + (it << 8);
    int k = e >> 3, rr = e & 7;
    int m = rr >> 1, p = rr & 1;
    s[m][SW(k + 256 * p)] = Tb[(size_t)k * NRHO + i0 + rr];
  }
  __syncthreads();
  // stage B: build Z = F0 + i*F1 over k=0..511 (registers to avoid in-place hazard)
  float2 Zr[8];
  for (int it = 0; it < 8; ++it) {
    int e = tid + (it << 8);
    int m = e >> 9, k = e & 511;
    float2 z;
    if (k == 256) z = make_float2(0.f, 0.f);
    else {
      int k2 = (k < 256) ? k : 512 - k;
      float2 F0 = s[m][SW(k2)];
      float2 F1 = s[m][SW(256 + k2)];
      if (k2 == 0) { F0.y = 0.f; F1.y = 0.f; }       // numpy irfft ignores DC imag
      if (k < 256) z = make_float2(F0.x - F1.y, F0.y + F1.x);
      else         z = make_float2(F0.x + F1.y, F1.x - F0.y);
    }
    Zr[it] = z;
  }
  __syncthreads();
  for (int it = 0; it < 8; ++it) {
    int e = tid + (it << 8);
    int m = e >> 9, k = e & 511;
    s[m][SW(k)] = Zr[it];
  }
  // fused inverse DIF pairs (8,7),(6,5),(4,3),(2,1)
  #pragma unroll
  for (int lh = 8; lh >= 2; lh -= 2) {
    __syncthreads();
    const int h = 1 << (lh - 1);                     // half of stage-lh span
    #pragma unroll
    for (int it = 0; it < 2; ++it) {
      int e = tid + (it << 8);                       // 0..511
      int m = e >> 7, gq = e & 127;
      int pos = gq & (h - 1);
      int base = ((gq >> (lh - 1)) << (lh + 1)) | pos;
      float2 wa = twl[pos << (8 - lh)];
      float2 w2 = twl[pos << (9 - lh)];
      float2* sm = s[m];
      float2 a = sm[SW(base)];
      float2 b = sm[SW(base + h)];
      float2 c = sm[SW(base + 2 * h)];
      float2 d = sm[SW(base + 3 * h)];
      // stage lh (span 2h): pairs (a,c),(b,d); odd-pair w = -i*wa -> conj mult by +i
      float2 ap = make_float2(a.x + c.x, a.y + c.y);
      float2 cp = cmulcf(make_float2(a.x - c.x, a.y - c.y), wa);
      float2 bp = make_float2(b.x + d.x, b.y + d.y);
      float2 tt = cmulcf(make_float2(b.x - d.x, b.y - d.y), wa);
      float2 dp = make_float2(-tt.y, tt.x);          // (+i)*cmulcf(b-d, wa)
      // stage lh-1 (span h): pairs (ap,bp),(cp,dp), same w2
      sm[SW(base)]         = make_float2(ap.x + bp.x, ap.y + bp.y);
      sm[SW(base + h)]     = cmulcf(make_float2(ap.x - bp.x, ap.y - bp.y), w2);
      sm[SW(base + 2 * h)] = make_float2(cp.x + dp.x, cp.y + dp.y);
      sm[SW(base + 3 * h)] = cmulcf(make_float2(cp.x - dp.x, cp.y - dp.y), w2);
    }
  }
  // final radix-2 stage lh=0 (w = twl[0] = 1)
  __syncthreads();
  #pragma unroll
  for (int it = 0; it < 4; ++it) {
    int e = tid + (it << 8);
    int m = e >> 8, b = e & 255;
    int ia = b << 1;
    float2* sm = s[m];
    float2 u = sm[SW(ia)];
    float2 v = sm[SW(ia + 1)];
    sm[SW(ia)]     = make_float2(u.x + v.x, u.y + v.y);
    sm[SW(ia + 1)] = make_float2(u.x - v.x, u.y - v.y);
  }
  __syncthreads();
  // write ONLY theta rows 128..383, compacted+natural order (2048 values)
  float* gb = gkT + (size_t)(span * gridDim.y + lb) * (GROWS * NRHO);
  for (int it = 0; it < 8; ++it) {
    int e = tid + (it << 8);                         // 0..2047
    int ro = e >> 3, rr = e & 7;                     // ro = j-128
    int j = ro + 128;
    int jslot = __brev((unsigned)j) >> 23;           // DIF output slot of theta j
    float2 z = s[rr >> 1][SW(jslot)];
    gb[(size_t)ro * NRHO + i0 + rr] = (rr & 1) ? z.y : z.x;
  }
}

// ---------------- resample to (angle, det), ALL spans in one dispatch ----------------
// Span of angle t: k = (3t)>>10 (exact partition; boundaries never integral).
// gkT rows are compacted: row = fx - 128 (fx proven in [128,384)).
__global__ __launch_bounds__(256) void k_scatter(const float* __restrict__ gkT,
                                                 float* __restrict__ out,
                                                 int b0, int chunk,
                                                 double d_rho, double aR) {
  int p = blockIdx.x * 256 + threadIdx.x;
  if (p >= PTOT) return;
  const int t = p >> 9;
  const int d = p & 511;
  const int span = (3 * t) >> 10;
  const double beta = M_PI / 3.0;
  double th0 = (double)t * M_PI / 1024.0 - beta / 2.0;
  double th00 = th0 - (double)span * beta;
  double d_th = 2.0 * beta / 512.0;
  double th_lp0 = -256.0 * d_th, th_lpL = 255.0 * d_th;
  double p1 = (th00 - th_lp0) / (th_lpL - th_lp0) * 511.0;
  double s0v = (d == 511) ? 1.0 : (double)d * (2.0 / 511.0) - 1.0;
  double p2 = log(s0v * aR + (1.0 - aR) * cos(th00));
  double rho0 = -1024.0 * d_rho, rhoL = -1.0 * d_rho;
  p2 = (p2 - rho0) / (rhoL - rho0) * 1023.0;
  double fy = floor(p2); fy = fy < 0.0 ? 0.0 : (fy > 1022.0 ? 1022.0 : fy);
  double fx = floor(p1); fx = fx < 0.0 ? 0.0 : (fx > 510.0 ? 510.0 : fx);
  int idx = ((int)fx - 128) * 1024 + (int)fy;        // compacted natural-order row
  const float* gsp = gkT + (size_t)span * chunk * (GROWS * NRHO);
  for (int lb = 0; lb < chunk; ++lb)
    out[(size_t)(b0 + lb) * PTOT + p] = gsp[(size_t)lb * (GROWS * NRHO) + idx];
}

// ---------------- launch ----------------
extern "C" void kernel_launch(void* const* d_in, const int* in_sizes, int n_in,
                              void* d_out, int out_size, void* d_ws, size_t ws_size,
                              hipStream_t stream) {
  (void)n_in; (void)out_size;
  const float* x = (const float*)d_in[0];
  float* out = (float*)d_out;
  const int batch = in_sizes[0] / (NIMG * NIMG);

  const size_t zeta_b = (size_t)ZROWS * NRHO * sizeof(float2);          // 2 MB
  const size_t idx_b  = (size_t)NSPAN * NRHO * NTH * sizeof(int);       // 6 MB
  const size_t tab_b  = 2048 * sizeof(double) * 2 + 1024 * sizeof(float2) * 2;
  const size_t per_b  = (size_t)NSPAN * ((size_t)ZROWS * NRHO * sizeof(float2)
                      + (size_t)GROWS * NRHO * sizeof(float));          // 9 MB / image
  int chunk = batch;
  while (chunk > 1 && zeta_b + idx_b + tab_b + (size_t)chunk * per_b > ws_size) chunk >>= 1;

  char* ws = (char*)d_ws;
  float2* zetaT   = (float2*)ws;  ws += zeta_b;
  int*    idx1    = (int*)ws;     ws += idx_b;
  double* Ltab    = (double*)ws;  ws += 2048 * sizeof(double);
  double* amp     = (double*)ws;  ws += 2048 * sizeof(double);
  float2* tw1024f = (float2*)ws;  ws += 1024 * sizeof(float2);
  float2* tw2048f = (float2*)ws;  ws += 1024 * sizeof(float2);
  float2* T       = (float2*)ws;  ws += (size_t)NSPAN * chunk * ZROWS * NRHO * sizeof(float2);
  float*  gkT     = (float*)ws;

  k_pre     <<<dim3(8),    dim3(256), 0, stream>>>(Ltab, amp, tw1024f, tw2048f);
  k_zeta    <<<dim3(1024), dim3(256), 0, stream>>>(Ltab, amp, tw2048f, zetaT,
                                                   g_C.G_LA, g_C.dth, g_C.constv);
  k_idx_lp2c<<<dim3((NSPAN * NRHO * NTH) / 256), dim3(256), 0, stream>>>(idx1, g_C.d_rho, g_C.aR);

  for (int b0 = 0; b0 < batch; b0 += chunk) {
    int c = (b0 + chunk <= batch) ? chunk : (batch - b0);
    k_gather_rfft<<<dim3(NRHO / 8, c, NSPAN), dim3(256), 0, stream>>>(x, idx1, tw1024f, T, b0, g_C.d_rho);
    k_fft_rho    <<<dim3(ZROWS / 4, c, NSPAN), dim3(256), 0, stream>>>(T, zetaT, tw1024f);
    k_irfft_th   <<<dim3(NRHO / 8, c, NSPAN), dim3(256), 0, stream>>>(T, tw1024f, gkT);
    k_scatter    <<<dim3(PTOT / 256), dim3(256), 0, stream>>>(gkT, out, b0, c,
                                                              g_C.d_rho, g_C.aR);
  }
}

// Round 5
// 262.107 us; speedup vs baseline: 1.0969x; 1.0012x over previous
//
#include <hip/hip_runtime.h>
#include <cmath>

#ifndef M_PI
#define M_PI 3.14159265358979323846
#endif

#define NIMG 512
#define NRHO 1024
#define NTH  512
#define ZROWS 256           // theta bins kept (bin 256 zeroed by zeta -> dropped)
#define GROWS 256           // gk theta rows kept: fx in [128,384) only
#define S4   520            // LDS row stride (float2) for 4-row pair kernels
#define PTOT (1024*512)     // n_angles * n_det
#define NSPAN 3

// ---------------- host-side scalar constants ----------------
struct Consts { double G_LA, d_rho, aR, dth, constv; };

static Consts compute_consts() {
  Consts c;
  const double beta = M_PI / 3.0;
  const double sb = sin(beta / 2.0), cb = cos(beta / 2.0);
  const double aR = sb / (1.0 + sb);
  const double am = (cb - sb) / (1.0 + sb);
  double g = -1e300;
  const double start = -M_PI / 2.0, stop = M_PI / 2.0;
  const double delta = (stop - start) / 999.0;
  for (int i = 0; i < 1000; ++i) {
    double t = (i == 999) ? stop : (double)i * delta + start;
    double wre = aR * cos(t) + (1.0 - aR);
    double wim = aR * sin(t);
    double v = log(hypot(wre, wim)) + log(cos(beta / 2.0 - atan2(wim, wre)));
    if (!std::isnan(v) && v > g) g = v;
  }
  c.aR    = aR;
  c.G_LA  = g - log(am);
  c.d_rho = c.G_LA / 1024.0;
  double t1 = (-1023.0 / 2048.0) * beta * 2.0;
  double t0 = (-1024.0 / 2048.0) * beta * 2.0;
  c.dth = t1 - t0;
  c.constv = sqrt(0.5) * M_PI / 4.0 / aR / sqrt(2.0);
  return c;
}
static const Consts g_C = compute_consts();

// ---------------- device helpers ----------------
__device__ __forceinline__ float2 cmulf(float2 a, float2 b) {
  return make_float2(a.x * b.x - a.y * b.y, a.x * b.y + a.y * b.x);
}
__device__ __forceinline__ float2 cmulcf(float2 a, float2 w) {   // a * conj(w)
  return make_float2(a.x * w.x + a.y * w.y, a.y * w.x - a.x * w.y);
}
__device__ __forceinline__ int SW(int i) { return i ^ ((i >> 5) & 31); }  // XOR bank swizzle
__device__ __forceinline__ int PD(int i) { return i + (i >> 4); }         // pad-per-16 permutation
__device__ __forceinline__ int dr4_10(int v) {                    // reverse 5 base-4 digits
  int r = 0;
  #pragma unroll
  for (int k = 0; k < 5; ++k) { r = (r << 2) | (v & 3); v >>= 2; }
  return r;
}
// forward DIF radix-4 butterfly (inputs at digits 0..3, outputs pre-twiddle)
__device__ __forceinline__ void bf4f(float2 a, float2 b, float2 c, float2 d,
                                     float2& y0, float2& y1, float2& y2, float2& y3) {
  float2 A = make_float2(a.x + c.x, a.y + c.y);
  float2 C = make_float2(a.x - c.x, a.y - c.y);
  float2 B = make_float2(b.x + d.x, b.y + d.y);
  float2 D = make_float2(b.x - d.x, b.y - d.y);
  y0 = make_float2(A.x + B.x, A.y + B.y);
  y2 = make_float2(A.x - B.x, A.y - B.y);
  y1 = make_float2(C.x + D.y, C.y - D.x);   // C - iD
  y3 = make_float2(C.x - D.y, C.y + D.x);   // C + iD
}
// inverse DIT radix-4 butterfly (inputs already conj-twiddled)
__device__ __forceinline__ void bf4i(float2 u0, float2 u1, float2 u2, float2 u3,
                                     float2& z0, float2& z1, float2& z2, float2& z3) {
  float2 t0 = make_float2(u0.x + u2.x, u0.y + u2.y);
  float2 t1 = make_float2(u0.x - u2.x, u0.y - u2.y);
  float2 t2 = make_float2(u1.x + u3.x, u1.y + u3.y);
  float2 t3 = make_float2(u1.x - u3.x, u1.y - u3.y);
  z0 = make_float2(t0.x + t2.x, t0.y + t2.y);
  z2 = make_float2(t0.x - t2.x, t0.y - t2.y);
  z1 = make_float2(t1.x - t3.y, t1.y + t3.x);   // t1 + i t3
  z3 = make_float2(t1.x + t3.y, t1.y - t3.x);   // t1 - i t3
}
__device__ __forceinline__ double h_val(int jj) {
  const double ctab[11] = {-216254335.0, 679543284.0, -1412947389.0, 2415881496.0,
                           -3103579086.0, 2939942400.0, -2023224114.0, 984515304.0,
                           -321455811.0, 63253516.0, -5675265.0};
  int j = -1;
  if (jj <= 10) j = jj;
  else if (jj >= 2038) j = 2048 - jj;
  if (j < 0) return 1.0;
  double c = 1.0 + ctab[j] / 958003200.0;
  if (j == 0) c = 2.0 * (c - 0.5);
  return c;
}

// ---------------- precompute: L/amp tables + fp32 twiddle tables ----------------
__global__ __launch_bounds__(256) void k_pre(double* __restrict__ Ltab,
                                             double* __restrict__ amp,
                                             float2* __restrict__ tw1024f,
                                             float2* __restrict__ tw2048f) {
  int id = blockIdx.x * 256 + threadIdx.x;
  const double beta = M_PI / 3.0;
  if (id < 2048) {
    double th = ((double)(id - 1024) / 2048.0) * beta * 2.0;
    double L = log(cos(th));
    Ltab[id] = L;
    amp[id]  = h_val(id) * exp(-L);
  }
  if (id < 1024) {
    double a1 = -2.0 * M_PI * (double)id / 1024.0;
    double a2 = -2.0 * M_PI * (double)id / 2048.0;
    double s1, c1, s2, c2;
    sincos(a1, &s1, &c1); sincos(a2, &s2, &c2);
    tw1024f[id] = make_float2((float)c1, (float)s1);
    tw2048f[id] = make_float2((float)c2, (float)s2);
  }
}

// ---------------- zeta: fp32 2048-pt FFT per rho-frequency row ----------------
// zetaT[j][pp], j<256 theta bin; pp = PERM(dr4_10(rho freq)) where
// PERM(p) = ((p&15)<<6)|(p>>4) matches k_fft_rho's middle-pass coalesced read.
// Includes const*dth/b3 and both inverse-FFT normalizations.
__global__ __launch_bounds__(256) void k_zeta(const double* __restrict__ Ltab,
                                              const double* __restrict__ amp,
                                              const float2* __restrict__ tw2048f,
                                              float2* __restrict__ zetaT,
                                              double G_LA, double dth, double constv) {
  __shared__ float2 s[2048 + 128];
  __shared__ float2 twl[1024 + 64];
  const int i   = blockIdx.x;    // k_rho row 0..1023
  const int tid = threadIdx.x;
  for (int e = tid; e < 1024; e += 256) twl[PD(e)] = tw2048f[e];
  const double om = 2.0 * M_PI * (double)(i - 512) / G_LA;
  const double INV2PI = 1.0 / (2.0 * M_PI);
  for (int j = tid; j < 2048; j += 256) {
    int jj = (j + 1024) & 2047;
    double ph = -om * Ltab[jj] * INV2PI;
    ph -= floor(ph);
    float ang = (float)ph * 6.28318530717958647f;
    float sv, cv; __sincosf(ang, &sv, &cv);
    float a = (float)amp[jj];
    s[PD(__brev((unsigned)j) >> 21)] = make_float2(a * cv, a * sv);
  }
  for (int lh = 0; lh < 11; ++lh) {
    __syncthreads();
    for (int e = tid; e < 1024; e += 256) {
      int pos = e & ((1 << lh) - 1);
      int ia  = ((e >> lh) << (lh + 1)) | pos;
      float2 w = twl[PD(pos << (10 - lh))];
      float2 u = s[PD(ia)];
      float2 v = cmulf(s[PD(ia + (1 << lh))], w);
      s[PD(ia)]             = make_float2(u.x + v.x, u.y + v.y);
      s[PD(ia + (1 << lh))] = make_float2(u.x - v.x, u.y - v.y);
    }
  }
  __syncthreads();
  const int i2 = (i + 512) & 1023;
  const int p  = dr4_10(i2);
  const int pp = ((p & 15) << 6) | (p >> 4);          // middle-pass coalescing permute
  const double b3r = (4.0 + 2.0 * cos(2.0 * M_PI * (double)i2 / 1024.0)) / 6.0;
  if (tid < 256) {
    int j2 = tid;
    float2 z = make_float2(0.f, 0.f);
    if (i != 0) {
      float2 F = s[PD(j2)];
      double b3t = (4.0 + 2.0 * cos(2.0 * M_PI * (double)j2 / 512.0)) / 6.0;
      double sc = dth * constv / (b3r * b3t) * (1.0 / (1024.0 * 512.0));
      z = make_float2((float)((double)F.x * sc), (float)((double)F.y * sc));
    }
    zetaT[(size_t)j2 * 1024 + pp] = z;
  }
}

// ---------------- gather index map, ALL spans, natural theta order ----------------
__global__ __launch_bounds__(256) void k_idx_lp2c(int* __restrict__ idx1,
                                                  double d_rho, double aR) {
  int q = blockIdx.x * 256 + threadIdx.x;
  int span = q >> 19;                                // q / (NRHO*NTH)
  int ql = q & (NRHO * NTH - 1);
  int i = ql >> 9, j = ql & 511;
  const double beta = M_PI / 3.0;
  double d_th = 2.0 * beta / 512.0;
  double th = (double)(j - 256) * d_th;
  double er = exp((double)(i - 1024) * d_rho);
  double t1 = er * cos(th), t2 = er * sin(th);
  double a = (double)span * beta + beta / 2.0;
  double ca = cos(a), sa = sin(a);
  double l1 = ((t1 - (1.0 - aR)) * ca - t2 * sa) / aR;
  double l2 = -(((t1 - (1.0 - aR)) * sa + t2 * ca) / aR);
  l1 = (l1 + 1.0) / 2.0 * 511.0;
  l2 = (l2 + 1.0) / 2.0 * 511.0;
  double fy = floor(l1); fy = fy < 0.0 ? 0.0 : (fy > 510.0 ? 510.0 : fy);
  double fx = floor(l2); fx = fx < 0.0 ? 0.0 : (fx > 510.0 ? 510.0 : fx);
  idx1[q] = (int)fy * 512 + (int)fx;
}

// ---------------- gather + paired rfft(512): 8 rho-rows = 4 complex FFTs ----------------
// Gather remapped for L2-line locality: wave w owns rho rows {2w, 2w+1}; each gather
// instruction reads 64 CONSECUTIVE thetas of ONE row (a short arc in the image,
// ~4-16 cache lines vs ~64 with the old sparse-ring pattern). Staging slots and all
// FFT stages identical to before.
__global__ __launch_bounds__(256) void k_gather_rfft(const float* __restrict__ x,
                                                     const int* __restrict__ idx1,
                                                     const float2* __restrict__ tw1024f,
                                                     float2* __restrict__ T,
                                                     int b0, double d_rho) {
  __shared__ float2 s[4][S4];     // 16.6 KB
  __shared__ float2 twl[256];
  const int bx   = blockIdx.x;
  const int g    = ((bx & 7) << 4) | (bx >> 3);      // XCD ring swizzle (128 blocks)
  const int i0   = g * 8;
  const int lb   = blockIdx.y;
  const int span = blockIdx.z;
  const int tid  = threadIdx.x;
  twl[tid] = tw1024f[2 * tid];                       // exp(-2pi i m/512), m<256
  const int w  = tid >> 6;                           // wave 0..3 -> rows 2w, 2w+1
  const int l6 = tid & 63;
  const float er0 = (float)exp((double)(i0 + 2 * w     - 1024) * d_rho);
  const float er1 = (float)exp((double)(i0 + 2 * w + 1 - 1024) * d_rho);
  const float* xb = x + (size_t)(b0 + lb) * (NIMG * NIMG);
  const int* ip0 = idx1 + span * (NRHO * NTH) + (i0 + 2 * w) * 512;
  const int* ip1 = ip0 + 512;
  int id0[8], id1[8];
  #pragma unroll
  for (int u = 0; u < 8; ++u) {                      // coalesced 256B idx loads
    id0[u] = ip0[l6 + 64 * u];
    id1[u] = ip1[l6 + 64 * u];
  }
  float v0[8], v1[8];
  #pragma unroll
  for (int u = 0; u < 8; ++u) {                      // 16 arc-local gathers in flight
    v0[u] = xb[id0[u]];
    v1[u] = xb[id1[u]];
  }
  float* sm = (float*)s[w];                          // pair m = w holds rows 2w,2w+1
  #pragma unroll
  for (int u = 0; u < 8; ++u) {
    int j = l6 + 64 * u;
    int slot = __brev((unsigned)j) >> 23;            // bit-reversal for free
    sm[2 * SW(slot) + 0] = v0[u] * er0;
    sm[2 * SW(slot) + 1] = v1[u] * er1;
  }
  // fused radix-4 stages (0,1),(2,3),(4,5),(6,7)
  #pragma unroll
  for (int lh = 0; lh < 8; lh += 2) {
    __syncthreads();
    const int q = 1 << lh;
    #pragma unroll
    for (int it = 0; it < 2; ++it) {
      int e = tid + (it << 8);                       // 0..511
      int m = e >> 7, gq = e & 127;
      int pos = gq & (q - 1);
      int base = ((gq >> lh) << (lh + 2)) | pos;
      float2 w1 = twl[pos << (8 - lh)];
      float2 w2 = twl[pos << (7 - lh)];
      float2* smm = s[m];
      float2 a = smm[SW(base)];
      float2 b = smm[SW(base + q)];
      float2 c = smm[SW(base + 2 * q)];
      float2 d = smm[SW(base + 3 * q)];
      float2 wb = cmulf(b, w1), wd = cmulf(d, w1);
      float2 t0 = make_float2(a.x + wb.x, a.y + wb.y);
      float2 t1 = make_float2(a.x - wb.x, a.y - wb.y);
      float2 t2 = make_float2(c.x + wd.x, c.y + wd.y);
      float2 t3 = make_float2(c.x - wd.x, c.y - wd.y);
      float2 z2 = cmulf(t2, w2);
      float2 p3 = cmulf(t3, w2);
      float2 z3 = make_float2(p3.y, -p3.x);          // (-i)*(w2*t3)
      smm[SW(base)]         = make_float2(t0.x + z2.x, t0.y + z2.y);
      smm[SW(base + 2 * q)] = make_float2(t0.x - z2.x, t0.y - z2.y);
      smm[SW(base + q)]     = make_float2(t1.x + z3.x, t1.y + z3.y);
      smm[SW(base + 3 * q)] = make_float2(t1.x - z3.x, t1.y - z3.y);
    }
  }
  // final radix-2 stage lh=8
  __syncthreads();
  #pragma unroll
  for (int it = 0; it < 4; ++it) {
    int e = tid + (it << 8);
    int m = e >> 8, b = e & 255;                     // pos=b, ia=b
    float2 w2 = twl[b];
    float2* smm = s[m];
    float2 u = smm[SW(b)];
    float2 vv = cmulf(smm[SW(b + 256)], w2);
    smm[SW(b)]       = make_float2(u.x + vv.x, u.y + vv.y);
    smm[SW(b + 256)] = make_float2(u.x - vv.x, u.y - vv.y);
  }
  __syncthreads();
  // unpack pair spectra + transposed coalesced write (64B per theta bin)
  float2* Tb = T + (size_t)(span * gridDim.y + lb) * (ZROWS * NRHO);
  for (int it = 0; it < 8; ++it) {
    int e = tid + (it << 8);                         // 0..2047
    int k = e >> 3, rr = e & 7;
    int m = rr >> 1, pp = rr & 1;
    float2 Z  = s[m][SW(k)];
    float2 Zc = s[m][SW((512 - k) & 511)];
    float2 F;
    if (!pp) F = make_float2(0.5f * (Z.x + Zc.x), 0.5f * (Z.y - Zc.y));
    else     F = make_float2(0.5f * (Z.y + Zc.y), 0.5f * (Zc.x - Z.x));
    Tb[(size_t)k * NRHO + i0 + rr] = F;
  }
}

// ---------------- rho: fft1024 * zeta * ifft1024, register radix-16, 4 bins/block ----
// Each thread owns 16 points r[c][a] = row[t6 + 64a + 256c] of ONE bin (64 thr/bin).
// Stage plan (radix-4 DIF lq=8,6,4,2,0 / DIT lq=0,2,4,6,8 — identical semantics to
// the 5-stage loop version, pairs fused in registers):
//   fwd(8,6) from GLOBAL -> LDS; fwd(4,2) LDS round-trip;
//   [fwd(0) + zeta + inv(0)] one LDS round-trip (zeta pre-permuted by k_zeta);
//   inv(2,4) LDS round-trip; inv(6,8) LDS -> GLOBAL.
// 4 LDS round-trips / 5 barriers vs 11 round-trips / 11 barriers.
__global__ __launch_bounds__(256) void k_fft_rho(float2* __restrict__ T,
                                                 const float2* __restrict__ zetaT,
                                                 const float2* __restrict__ tw1024f) {
  __shared__ float2 s[4][1024 + 64];
  __shared__ float2 twl[1024 + 64];
  const int j0   = blockIdx.x * 4;                   // four theta bins per block
  const int lb   = blockIdx.y;
  const int span = blockIdx.z;
  const int tid  = threadIdx.x;
  const int bin  = tid >> 6;
  const int t6   = tid & 63;
  float2* rowb = T + ((size_t)(span * gridDim.y + lb) * ZROWS + j0 + bin) * NRHO;

  // global load, coalesced 512B per (a,c): r[c][a] = rowb[t6 + 64a + 256c]
  float2 r[4][4];
  #pragma unroll
  for (int c = 0; c < 4; ++c)
    #pragma unroll
    for (int a = 0; a < 4; ++a)
      r[c][a] = rowb[t6 + 64 * a + 256 * c];

  for (int e = tid; e < 1024; e += 256) twl[PD(e)] = tw1024f[e];
  __syncthreads();

  // ---- fwd fused (lq=8 then lq=6) in registers
  #pragma unroll
  for (int a = 0; a < 4; ++a) {                      // lq=8: over c, jj = t6+64a, tfac=1
    int jj = t6 + 64 * a;
    float2 y0, y1, y2, y3;
    bf4f(r[0][a], r[1][a], r[2][a], r[3][a], y0, y1, y2, y3);
    r[0][a] = y0;
    r[1][a] = cmulf(y1, twl[PD(jj)]);
    r[2][a] = cmulf(y2, twl[PD(2 * jj)]);
    r[3][a] = cmulf(y3, twl[PD(3 * jj)]);
  }
  {                                                  // lq=6: over a, jj = t6, tfac=4
    float2 w1 = twl[PD(4 * t6)], w2 = twl[PD(8 * t6)], w3 = twl[PD(12 * t6)];
    #pragma unroll
    for (int c = 0; c < 4; ++c) {
      float2 y0, y1, y2, y3;
      bf4f(r[c][0], r[c][1], r[c][2], r[c][3], y0, y1, y2, y3);
      r[c][0] = y0; r[c][1] = cmulf(y1, w1); r[c][2] = cmulf(y2, w2); r[c][3] = cmulf(y3, w3);
    }
  }
  #pragma unroll
  for (int c = 0; c < 4; ++c)
    #pragma unroll
    for (int a = 0; a < 4; ++a)
      s[bin][PD(t6 + 64 * a + 256 * c)] = r[c][a];
  __syncthreads();

  // ---- fwd fused (lq=4 then lq=2): set {64*B64 + b2 + 4a + 16c}
  const int B64 = t6 >> 2, b2 = t6 & 3;
  const int fbase = 64 * B64 + b2;
  #pragma unroll
  for (int c = 0; c < 4; ++c)
    #pragma unroll
    for (int a = 0; a < 4; ++a)
      r[c][a] = s[bin][PD(fbase + 4 * a + 16 * c)];
  #pragma unroll
  for (int a = 0; a < 4; ++a) {                      // lq=4: over c, jj = b2+4a, tfac=16
    int ji = 16 * (b2 + 4 * a);
    float2 y0, y1, y2, y3;
    bf4f(r[0][a], r[1][a], r[2][a], r[3][a], y0, y1, y2, y3);
    r[0][a] = y0;
    r[1][a] = cmulf(y1, twl[PD(ji)]);
    r[2][a] = cmulf(y2, twl[PD(2 * ji)]);
    r[3][a] = cmulf(y3, twl[PD(3 * ji)]);
  }
  {                                                  // lq=2: over a, jj = b2, tfac=64
    float2 w1 = twl[PD(64 * b2)], w2 = twl[PD(128 * b2)], w3 = twl[PD(192 * b2)];
    #pragma unroll
    for (int c = 0; c < 4; ++c) {
      float2 y0, y1, y2, y3;
      bf4f(r[c][0], r[c][1], r[c][2], r[c][3], y0, y1, y2, y3);
      r[c][0] = y0; r[c][1] = cmulf(y1, w1); r[c][2] = cmulf(y2, w2); r[c][3] = cmulf(y3, w3);
    }
  }
  #pragma unroll
  for (int c = 0; c < 4; ++c)
    #pragma unroll
    for (int a = 0; a < 4; ++a)
      s[bin][PD(fbase + 4 * a + 16 * c)] = r[c][a];
  __syncthreads();

  // ---- middle: fwd lq=0 + zeta + inv lq=0 on 4 consecutive quads {16*t6 + 4u + v}
  {
    const float2* zp = zetaT + (size_t)(j0 + bin) * NRHO;   // PERMUTED rows (k_zeta)
    #pragma unroll
    for (int u = 0; u < 4; ++u) {
      int o0 = 16 * t6 + 4 * u;
      float2 a0 = s[bin][PD(o0)],     a1 = s[bin][PD(o0 + 1)];
      float2 a2 = s[bin][PD(o0 + 2)], a3 = s[bin][PD(o0 + 3)];
      float2 y0, y1, y2, y3;
      bf4f(a0, a1, a2, a3, y0, y1, y2, y3);
      float2 q0 = zp[64 * (4 * u + 0) + t6];         // coalesced: lanes t6 consecutive
      float2 q1 = zp[64 * (4 * u + 1) + t6];
      float2 q2 = zp[64 * (4 * u + 2) + t6];
      float2 q3 = zp[64 * (4 * u + 3) + t6];
      y0 = cmulf(y0, q0); y1 = cmulf(y1, q1); y2 = cmulf(y2, q2); y3 = cmulf(y3, q3);
      float2 z0, z1, z2, z3;
      bf4i(y0, y1, y2, y3, z0, z1, z2, z3);          // inv lq=0, w=1
      s[bin][PD(o0)]     = z0; s[bin][PD(o0 + 1)] = z1;
      s[bin][PD(o0 + 2)] = z2; s[bin][PD(o0 + 3)] = z3;
    }
  }
  __syncthreads();

  // ---- inv fused (lq=2 then lq=4): set {64*B64 + b2 + 4a + 16c}
  #pragma unroll
  for (int c = 0; c < 4; ++c)
    #pragma unroll
    for (int a = 0; a < 4; ++a)
      r[c][a] = s[bin][PD(fbase + 4 * a + 16 * c)];
  {                                                  // lq=2: over a, jj = b2, tfac=64
    float2 w1 = twl[PD(64 * b2)], w2 = twl[PD(128 * b2)], w3 = twl[PD(192 * b2)];
    #pragma unroll
    for (int c = 0; c < 4; ++c) {
      float2 u1 = cmulcf(r[c][1], w1);
      float2 u2 = cmulcf(r[c][2], w2);
      float2 u3 = cmulcf(r[c][3], w3);
      bf4i(r[c][0], u1, u2, u3, r[c][0], r[c][1], r[c][2], r[c][3]);
    }
  }
  #pragma unroll
  for (int a = 0; a < 4; ++a) {                      // lq=4: over c, jj = b2+4a, tfac=16
    int ji = 16 * (b2 + 4 * a);
    float2 u1 = cmulcf(r[1][a], twl[PD(ji)]);
    float2 u2 = cmulcf(r[2][a], twl[PD(2 * ji)]);
    float2 u3 = cmulcf(r[3][a], twl[PD(3 * ji)]);
    bf4i(r[0][a], u1, u2, u3, r[0][a], r[1][a], r[2][a], r[3][a]);
  }
  #pragma unroll
  for (int c = 0; c < 4; ++c)
    #pragma unroll
    for (int a = 0; a < 4; ++a)
      s[bin][PD(fbase + 4 * a + 16 * c)] = r[c][a];
  __syncthreads();

  // ---- inv fused (lq=6 then lq=8): set {t6 + 64a + 256c}, write straight to global
  #pragma unroll
  for (int c = 0; c < 4; ++c)
    #pragma unroll
    for (int a = 0; a < 4; ++a)
      r[c][a] = s[bin][PD(t6 + 64 * a + 256 * c)];
  {                                                  // lq=6: over a, jj = t6, tfac=4
    float2 w1 = twl[PD(4 * t6)], w2 = twl[PD(8 * t6)], w3 = twl[PD(12 * t6)];
    #pragma unroll
    for (int c = 0; c < 4; ++c) {
      float2 u1 = cmulcf(r[c][1], w1);
      float2 u2 = cmulcf(r[c][2], w2);
      float2 u3 = cmulcf(r[c][3], w3);
      bf4i(r[c][0], u1, u2, u3, r[c][0], r[c][1], r[c][2], r[c][3]);
    }
  }
  #pragma unroll
  for (int a = 0; a < 4; ++a) {                      // lq=8: over c, jj = t6+64a, tfac=1
    int jj = t6 + 64 * a;
    float2 u1 = cmulcf(r[1][a], twl[PD(jj)]);
    float2 u2 = cmulcf(r[2][a], twl[PD(2 * jj)]);
    float2 u3 = cmulcf(r[3][a], twl[PD(3 * jj)]);
    bf4i(r[0][a], u1, u2, u3, r[0][a], r[1][a], r[2][a], r[3][a]);
  }
  #pragma unroll
  for (int c = 0; c < 4; ++c)
    #pragma unroll
    for (int a = 0; a < 4; ++a)
      rowb[t6 + 64 * a + 256 * c] = r[c][a];
}

// ---------------- paired Hermitian irfft(512): 8 rho-rows = 4 complex IFFTs ----------------
// Inverse DIF (sign +), natural in -> bit-reversed out. Stages (8,7),(6,5),(4,3),(2,1)
// fused as radix-4 in registers (odd-pair twiddle conj(-i*w) = +i*conj(w), free
// rotation), then single radix-2 stage lh=0. Only theta rows 128..383 written,
// COMPACTED (row j-128) and in natural theta order.
__global__ __launch_bounds__(256) void k_irfft_th(const float2* __restrict__ T,
                                                  const float2* __restrict__ tw1024f,
                                                  float* __restrict__ gkT) {
  __shared__ float2 s[4][S4];
  __shared__ float2 twl[256];
  const int i0   = blockIdx.x * 8;
  const int lb   = blockIdx.y;
  const int span = blockIdx.z;
  const int tid  = threadIdx.x;
  twl[tid] = tw1024f[2 * tid];
  const float2* Tb = T + (size_t)(span * gridDim.y + lb) * (ZROWS * NRHO);
  __syncthreads();
  // stage A: raw F -> LDS (pair m holds F0 at SW(k), F1 at SW(256+k))
  for (int it = 0; it < 8; ++it) {
    int e = tid + (it << 8);
    int k = e >> 3, rr = e & 7;
    int m = rr >> 1, p = rr & 1;
    s[m][SW(k + 256 * p)] = Tb[(size_t)k * NRHO + i0 + rr];
  }
  __syncthreads();
  // stage B: build Z = F0 + i*F1 over k=0..511 (registers to avoid in-place hazard)
  float2 Zr[8];
  for (int it = 0; it < 8; ++it) {
    int e = tid + (it << 8);
    int m = e >> 9, k = e & 511;
    float2 z;
    if (k == 256) z = make_float2(0.f, 0.f);
    else {
      int k2 = (k < 256) ? k : 512 - k;
      float2 F0 = s[m][SW(k2)];
      float2 F1 = s[m][SW(256 + k2)];
      if (k2 == 0) { F0.y = 0.f; F1.y = 0.f; }       // numpy irfft ignores DC imag
      if (k < 256) z = make_float2(F0.x - F1.y, F0.y + F1.x);
      else         z = make_float2(F0.x + F1.y, F1.x - F0.y);
    }
    Zr[it] = z;
  }
  __syncthreads();
  for (int it = 0; it < 8; ++it) {
    int e = tid + (it << 8);
    int m = e >> 9, k = e & 511;
    s[m][SW(k)] = Zr[it];
  }
  // fused inverse DIF pairs (8,7),(6,5),(4,3),(2,1)
  #pragma unroll
  for (int lh = 8; lh >= 2; lh -= 2) {
    __syncthreads();
    const int h = 1 << (lh - 1);                     // half of stage-lh span
    #pragma unroll
    for (int it = 0; it < 2; ++it) {
      int e = tid + (it << 8);                       // 0..511
      int m = e >> 7, gq = e & 127;
      int pos = gq & (h - 1);
      int base = ((gq >> (lh - 1)) << (lh + 1)) | pos;
      float2 wa = twl[pos << (8 - lh)];
      float2 w2 = twl[pos << (9 - lh)];
      float2* sm = s[m];
      float2 a = sm[SW(base)];
      float2 b = sm[SW(base + h)];
      float2 c = sm[SW(base + 2 * h)];
      float2 d = sm[SW(base + 3 * h)];
      // stage lh (span 2h): pairs (a,c),(b,d); odd-pair w = -i*wa -> conj mult by +i
      float2 ap = make_float2(a.x + c.x, a.y + c.y);
      float2 cp = cmulcf(make_float2(a.x - c.x, a.y - c.y), wa);
      float2 bp = make_float2(b.x + d.x, b.y + d.y);
      float2 tt = cmulcf(make_float2(b.x - d.x, b.y - d.y), wa);
      float2 dp = make_float2(-tt.y, tt.x);          // (+i)*cmulcf(b-d, wa)
      // stage lh-1 (span h): pairs (ap,bp),(cp,dp), same w2
      sm[SW(base)]         = make_float2(ap.x + bp.x, ap.y + bp.y);
      sm[SW(base + h)]     = cmulcf(make_float2(ap.x - bp.x, ap.y - bp.y), w2);
      sm[SW(base + 2 * h)] = make_float2(cp.x + dp.x, cp.y + dp.y);
      sm[SW(base + 3 * h)] = cmulcf(make_float2(cp.x - dp.x, cp.y - dp.y), w2);
    }
  }
  // final radix-2 stage lh=0 (w = twl[0] = 1)
  __syncthreads();
  #pragma unroll
  for (int it = 0; it < 4; ++it) {
    int e = tid + (it << 8);
    int m = e >> 8, b = e & 255;
    int ia = b << 1;
    float2* sm = s[m];
    float2 u = sm[SW(ia)];
    float2 v = sm[SW(ia + 1)];
    sm[SW(ia)]     = make_float2(u.x + v.x, u.y + v.y);
    sm[SW(ia + 1)] = make_float2(u.x - v.x, u.y - v.y);
  }
  __syncthreads();
  // write ONLY theta rows 128..383, compacted+natural order (2048 values)
  float* gb = gkT + (size_t)(span * gridDim.y + lb) * (GROWS * NRHO);
  for (int it = 0; it < 8; ++it) {
    int e = tid + (it << 8);                         // 0..2047
    int ro = e >> 3, rr = e & 7;                     // ro = j-128
    int j = ro + 128;
    int jslot = __brev((unsigned)j) >> 23;           // DIF output slot of theta j
    float2 z = s[rr >> 1][SW(jslot)];
    gb[(size_t)ro * NRHO + i0 + rr] = (rr & 1) ? z.y : z.x;
  }
}

// ---------------- resample to (angle, det), ALL spans in one dispatch ----------------
// Span of angle t: k = (3t)>>10 (exact partition; boundaries never integral).
// gkT rows are compacted: row = fx - 128 (fx proven in [128,384)).
__global__ __launch_bounds__(256) void k_scatter(const float* __restrict__ gkT,
                                                 float* __restrict__ out,
                                                 int b0, int chunk,
                                                 double d_rho, double aR) {
  int p = blockIdx.x * 256 + threadIdx.x;
  if (p >= PTOT) return;
  const int t = p >> 9;
  const int d = p & 511;
  const int span = (3 * t) >> 10;
  const double beta = M_PI / 3.0;
  double th0 = (double)t * M_PI / 1024.0 - beta / 2.0;
  double th00 = th0 - (double)span * beta;
  double d_th = 2.0 * beta / 512.0;
  double th_lp0 = -256.0 * d_th, th_lpL = 255.0 * d_th;
  double p1 = (th00 - th_lp0) / (th_lpL - th_lp0) * 511.0;
  double s0v = (d == 511) ? 1.0 : (double)d * (2.0 / 511.0) - 1.0;
  double p2 = log(s0v * aR + (1.0 - aR) * cos(th00));
  double rho0 = -1024.0 * d_rho, rhoL = -1.0 * d_rho;
  p2 = (p2 - rho0) / (rhoL - rho0) * 1023.0;
  double fy = floor(p2); fy = fy < 0.0 ? 0.0 : (fy > 1022.0 ? 1022.0 : fy);
  double fx = floor(p1); fx = fx < 0.0 ? 0.0 : (fx > 510.0 ? 510.0 : fx);
  int idx = ((int)fx - 128) * 1024 + (int)fy;        // compacted natural-order row
  const float* gsp = gkT + (size_t)span * chunk * (GROWS * NRHO);
  for (int lb = 0; lb < chunk; ++lb)
    out[(size_t)(b0 + lb) * PTOT + p] = gsp[(size_t)lb * (GROWS * NRHO) + idx];
}

// ---------------- launch ----------------
extern "C" void kernel_launch(void* const* d_in, const int* in_sizes, int n_in,
                              void* d_out, int out_size, void* d_ws, size_t ws_size,
                              hipStream_t stream) {
  (void)n_in; (void)out_size;
  const float* x = (const float*)d_in[0];
  float* out = (float*)d_out;
  const int batch = in_sizes[0] / (NIMG * NIMG);

  const size_t zeta_b = (size_t)ZROWS * NRHO * sizeof(float2);          // 2 MB
  const size_t idx_b  = (size_t)NSPAN * NRHO * NTH * sizeof(int);       // 6 MB
  const size_t tab_b  = 2048 * sizeof(double) * 2 + 1024 * sizeof(float2) * 2;
  const size_t per_b  = (size_t)NSPAN * ((size_t)ZROWS * NRHO * sizeof(float2)
                      + (size_t)GROWS * NRHO * sizeof(float));          // 9 MB / image
  int chunk = batch;
  while (chunk > 1 && zeta_b + idx_b + tab_b + (size_t)chunk * per_b > ws_size) chunk >>= 1;

  char* ws = (char*)d_ws;
  float2* zetaT   = (float2*)ws;  ws += zeta_b;
  int*    idx1    = (int*)ws;     ws += idx_b;
  double* Ltab    = (double*)ws;  ws += 2048 * sizeof(double);
  double* amp     = (double*)ws;  ws += 2048 * sizeof(double);
  float2* tw1024f = (float2*)ws;  ws += 1024 * sizeof(float2);
  float2* tw2048f = (float2*)ws;  ws += 1024 * sizeof(float2);
  float2* T       = (float2*)ws;  ws += (size_t)NSPAN * chunk * ZROWS * NRHO * sizeof(float2);
  float*  gkT     = (float*)ws;

  k_pre     <<<dim3(8),    dim3(256), 0, stream>>>(Ltab, amp, tw1024f, tw2048f);
  k_zeta    <<<dim3(1024), dim3(256), 0, stream>>>(Ltab, amp, tw2048f, zetaT,
                                                   g_C.G_LA, g_C.dth, g_C.constv);
  k_idx_lp2c<<<dim3((NSPAN * NRHO * NTH) / 256), dim3(256), 0, stream>>>(idx1, g_C.d_rho, g_C.aR);

  for (int b0 = 0; b0 < batch; b0 += chunk) {
    int c = (b0 + chunk <= batch) ? chunk : (batch - b0);
    k_gather_rfft<<<dim3(NRHO / 8, c, NSPAN), dim3(256), 0, stream>>>(x, idx1, tw1024f, T, b0, g_C.d_rho);
    k_fft_rho    <<<dim3(ZROWS / 4, c, NSPAN), dim3(256), 0, stream>>>(T, zetaT, tw1024f);
    k_irfft_th   <<<dim3(NRHO / 8, c, NSPAN), dim3(256), 0, stream>>>(T, tw1024f, gkT);
    k_scatter    <<<dim3(PTOT / 256), dim3(256), 0, stream>>>(gkT, out, b0, c,
                                                              g_C.d_rho, g_C.aR);
  }
}